// Round 8
// baseline (1057.352 us; speedup 1.0000x reference)
//
#include <hip/hip_runtime.h>
#include <hip/hip_bf16.h>
#include <math.h>

#define G 4
#define S 2048
#define MDIM 1024
#define E 8
#define HDIM 4096
#define TOPK 2
#define CAP 640
#define GC (G*CAP)      /* 2560 rows per expert */

typedef __attribute__((ext_vector_type(8))) short bf16x8;
typedef __attribute__((ext_vector_type(4))) short s16x4;
typedef __attribute__((ext_vector_type(4))) float f32x4;
typedef unsigned int u32;
typedef unsigned short u16;

#define MFMA16(a,b,c) __builtin_amdgcn_mfma_f32_16x16x32_bf16(a,b,c,0,0,0)
#define BAR() __builtin_amdgcn_s_barrier()

__device__ __forceinline__ u16 f2bf(float f) {
    union { float f; u32 u; } v; v.f = f;
    u32 r = v.u + 0x7fffu + ((v.u >> 16) & 1u);
    return (u16)(r >> 16);
}

__device__ __forceinline__ void gload16(const char* gp, char* lp) {
    __builtin_amdgcn_global_load_lds((const __attribute__((address_space(1))) u32*)gp,
                                     (__attribute__((address_space(3))) u32*)lp,
                                     16, 0, 0);
}

// swizzle for 64-byte LDS rows (XOR involution, applied to global src + LDS read)
__device__ __forceinline__ int swzb(int r) { return ((r >> 1) & 3) << 4; }

// ---------------- weight transpose + f32->bf16 convert (64x64, R5-proven) ----
__global__ __launch_bounds__(256) void transpose_cvt(const float* __restrict__ in,
                                                     u16* __restrict__ out, int R, int C) {
    int e = blockIdx.z;
    const float* ine = in + (size_t)e * R * C;
    u16* oute = out + (size_t)e * R * C;
    __shared__ float tile[64][68];
    int t = threadIdx.x;
    int x0 = blockIdx.x * 64, y0 = blockIdx.y * 64;
    int lx = (t & 15) * 4, ly = t >> 4;
    #pragma unroll
    for (int i = 0; i < 4; ++i) {
        f32x4 v = *(const f32x4*)(ine + (size_t)(y0 + ly + i * 16) * C + x0 + lx);
        *(f32x4*)&tile[ly + i * 16][lx] = v;
    }
    __syncthreads();
    int rr0 = (t & 15) * 4, cb = t >> 4;
    #pragma unroll
    for (int p = 0; p < 4; ++p) {
        int cc = cb + p * 16;
        s16x4 pk;
        #pragma unroll
        for (int j = 0; j < 4; ++j) pk[j] = (short)f2bf(tile[rr0 + j][cc]);
        *(s16x4*)(oute + (size_t)(x0 + cc) * R + y0 + rr0) = pk;
    }
}

// ---------------- router ----------------
__global__ __launch_bounds__(256) void router_kernel(const float* __restrict__ inp,
                                                     const float* __restrict__ rw,
                                                     int* __restrict__ top_i,
                                                     float* __restrict__ top_p,
                                                     float* __restrict__ partials) {
    int wid = threadIdx.x >> 6, lane = threadIdx.x & 63;
    int tok = blockIdx.x * 4 + wid;
    const float* x = inp + (size_t)tok * MDIM;
    float acc[E] = {0.f,0.f,0.f,0.f,0.f,0.f,0.f,0.f};
    #pragma unroll
    for (int rep = 0; rep < 4; ++rep) {
        int m0 = rep * 256 + lane * 4;
        f32x4 xv = *(const f32x4*)(x + m0);
        #pragma unroll
        for (int j = 0; j < 4; ++j) {
            const float* r = rw + (size_t)(m0 + j) * E;
            float xj = xv[j];
            #pragma unroll
            for (int e = 0; e < E; ++e) acc[e] += xj * r[e];
        }
    }
    #pragma unroll
    for (int e = 0; e < E; ++e)
        #pragma unroll
        for (int off = 32; off; off >>= 1) acc[e] += __shfl_down(acc[e], off);

    __shared__ float part[4][17];
    if (lane == 0) {
        float mx = acc[0];
        #pragma unroll
        for (int e = 1; e < E; ++e) mx = fmaxf(mx, acc[e]);
        float p[E], sum = 0.f;
        #pragma unroll
        for (int e = 0; e < E; ++e) { p[e] = expf(acc[e] - mx); sum += p[e]; }
        float inv = 1.f / sum;
        #pragma unroll
        for (int e = 0; e < E; ++e) p[e] *= inv;
        float lse = logf(sum) + mx;
        int i0 = 0;
        #pragma unroll
        for (int e = 1; e < E; ++e) if (acc[e] > acc[i0]) i0 = e;
        int i1 = (i0 == 0) ? 1 : 0;
        #pragma unroll
        for (int e = 0; e < E; ++e) if (e != i0 && acc[e] > acc[i1]) i1 = e;
        top_i[tok*2+0] = i0; top_i[tok*2+1] = i1;
        top_p[tok*2+0] = p[i0]; top_p[tok*2+1] = p[i1];
        #pragma unroll
        for (int e = 0; e < E; ++e) { part[wid][e] = p[e]; part[wid][8+e] = 0.f; }
        part[wid][8+i0] = 1.f; part[wid][8+i1] = 1.f;
        part[wid][16] = lse * lse;
    }
    __syncthreads();
    if (threadIdx.x < 17) {
        float v = part[0][threadIdx.x] + part[1][threadIdx.x] +
                  part[2][threadIdx.x] + part[3][threadIdx.x];
        partials[(size_t)blockIdx.x * 17 + threadIdx.x] = v;
    }
}

__global__ __launch_bounds__(256) void reduce_partials(const float* __restrict__ partials,
                                                       float* __restrict__ sums) {
    int g = blockIdx.x, t = threadIdx.x;
    float loc[17];
    #pragma unroll
    for (int c = 0; c < 17; ++c) loc[c] = 0.f;
    for (int r = t; r < 1024; r += 256) {
        const float* pr = partials + ((size_t)g * 1024 + r) * 17;
        #pragma unroll
        for (int c = 0; c < 17; ++c) loc[c] += pr[c];
    }
    __shared__ float red[256];
    for (int c = 0; c < 17; ++c) {
        red[t] = loc[c]; __syncthreads();
        for (int off = 128; off; off >>= 1) {
            if (t < off) red[t] += red[t + off];
            __syncthreads();
        }
        if (t == 0) sums[g * 17 + c] = red[0];
        __syncthreads();
    }
}

__global__ void aux_final(const float* __restrict__ sums, float* __restrict__ out) {
    float lb = 0.f, z = 0.f;
    for (int g = 0; g < G; ++g) {
        for (int e = 0; e < E; ++e)
            lb += (sums[g*17 + 8 + e] / (float)S) * (sums[g*17 + e] / (float)S);
        z += sums[g*17 + 16];
    }
    lb = lb / (float)(G * E) * (float)(E * E);
    z /= (float)(G * S);
    out[(size_t)G * S * MDIM] = 0.01f * lb + 0.001f * z;
}

// ---------------- capacity scan ----------------
__global__ __launch_bounds__(256) void scan_kernel(const int* __restrict__ top_i,
                                                   const float* __restrict__ pad,
                                                   int* __restrict__ slot_token,
                                                   int* __restrict__ token_c) {
    int b = blockIdx.x; int g = b >> 3, e = b & 7;
    int t = threadIdx.x;
    __shared__ int sums[256];
    int base = t * 16;
    int run = 0; unsigned mask16 = 0; int loc[16];
    #pragma unroll
    for (int j = 0; j < 16; ++j) {
        int i = base + j; int s = i >> 1, k = i & 1;
        int ex = top_i[((size_t)(g * S + s)) * 2 + k];
        int m = (ex == e) && (pad[g * S + s] == 0.f);
        run += m; loc[j] = run; mask16 |= ((unsigned)m << j);
    }
    sums[t] = run; __syncthreads();
    for (int off = 1; off < 256; off <<= 1) {
        int v = (t >= off) ? sums[t - off] : 0;
        __syncthreads();
        sums[t] += v;
        __syncthreads();
    }
    int excl = sums[t] - run;
    #pragma unroll
    for (int j = 0; j < 16; ++j) {
        if ((mask16 >> j) & 1u) {
            int pos = excl + loc[j];
            if (pos <= CAP) {
                int i = base + j; int s = i >> 1, k = i & 1;
                slot_token[((size_t)(e * G + g)) * CAP + (pos - 1)] = s;
                token_c[((size_t)(g * S + s)) * 2 + k] = pos - 1;
            }
        }
    }
}

// ---------------- gather tokens -> X bf16 [E][GC][MDIM] ----------------
__global__ __launch_bounds__(128) void gather_kernel(const float* __restrict__ inp,
                                                     const int* __restrict__ slot_token,
                                                     u16* __restrict__ X) {
    int row = blockIdx.x;
    int t = threadIdx.x;
    int s = slot_token[row];
    int g = (row % GC) / CAP;
    bf16x8 v;
    if (s >= 0) {
        const float* src = inp + ((size_t)(g * S + s)) * MDIM + t * 8;
        f32x4 a = *(const f32x4*)src;
        f32x4 b = *(const f32x4*)(src + 4);
        #pragma unroll
        for (int j = 0; j < 4; ++j) { v[j] = (short)f2bf(a[j]); v[4+j] = (short)f2bf(b[j]); }
    } else {
        #pragma unroll
        for (int j = 0; j < 8; ++j) v[j] = 0;
    }
    *(bf16x8*)(X + (size_t)row * MDIM + t * 8) = v;
}

// ======================================================================
// GEMM1+2 fused: BM=256 BN=128 BK=32. A staged in ring-4 LDS (64 KiB);
// B (Wg,W0) loaded global->REGISTER per-lane in MFMA fragment layout,
// double-buffered one tile ahead (L2-resident, VMEM pipe). LDS pipe now
// carries only A: 64 reads + 16KB writes/tile < MFMA demand.
// One barrier per K-tile; counted vmcnt = #loads just issued (retires
// exactly B(t) and A-stage(t+1)).
// ======================================================================
__global__ __launch_bounds__(512, 1) void gemm_ffn12_v8(
        const u16* __restrict__ Xb, const u16* __restrict__ WgT,
        const u16* __restrict__ W0T, u16* __restrict__ Hb) {
    extern __shared__ char smem[];
    const int NK = MDIM / 32;                      // 32
    int bid = blockIdx.x;
    int swz = (bid & 7) * 320 + (bid >> 3);        // bijective (2560 % 8 == 0)
    int mt = swz % 10, nt = (swz / 10) & 31, e = swz / 320;
    const char* A  = (const char*)(Xb  + (size_t)e * GC * MDIM   + (size_t)mt * 256 * MDIM);
    const char* Bg = (const char*)(WgT + (size_t)e * HDIM * MDIM + (size_t)nt * 128 * MDIM);
    const char* B0 = (const char*)(W0T + (size_t)e * HDIM * MDIM + (size_t)nt * 128 * MDIM);
    int tid = threadIdx.x, w = tid >> 6, l = tid & 63;
    int wm = w >> 2, wn = w & 3;                   // 2M x 4N waves
    int rl = l >> 2, cch = (l & 3) * 16;
    int fr = l & 15, fg = l >> 4;
    int lswz = ((fr >> 1) & 3) << 4;

    // A staging (global_load_lds, swizzled source)
    int rA0 = (0 * 8 + w) * 16 + rl, rA1 = (1 * 8 + w) * 16 + rl;
    const char* gA0 = A + (size_t)rA0 * MDIM * 2 + (cch ^ swzb(rA0));
    const char* gA1 = A + (size_t)rA1 * MDIM * 2 + (cch ^ swzb(rA1));
    int baseA = (wm * 128 + fr) * 64 + ((fg * 16) ^ lswz);

    // B per-lane fragment pointers (row = wn*32 + fn*16 + fr, 8 bf16 at k-group fg)
    const char* pBg0 = Bg + (size_t)(wn * 32 + 0 * 16 + fr) * MDIM * 2 + fg * 16;
    const char* pBg1 = Bg + (size_t)(wn * 32 + 1 * 16 + fr) * MDIM * 2 + fg * 16;
    const char* pBo0 = B0 + (size_t)(wn * 32 + 0 * 16 + fr) * MDIM * 2 + fg * 16;
    const char* pBo1 = B0 + (size_t)(wn * 32 + 1 * 16 + fr) * MDIM * 2 + fg * 16;

    f32x4 ag[8][2], ao[8][2];
    #pragma unroll
    for (int i = 0; i < 8; ++i) {
        ag[i][0] = (f32x4){0,0,0,0}; ag[i][1] = (f32x4){0,0,0,0};
        ao[i][0] = (f32x4){0,0,0,0}; ao[i][1] = (f32x4){0,0,0,0};
    }

    auto stage = [&](int tt) {                     // 2 gloads (A only)
        int kk = tt * 64, b = tt & 3;
        gload16(gA0 + kk, smem + b * 16384 + (0 * 8 + w) * 1024);
        gload16(gA1 + kk, smem + b * 16384 + (1 * 8 + w) * 1024);
    };

    bf16x8 bgA[2], boA[2], bgB[2], boB[2];

    // prologue: stage A(0),A(1); load B(0); retire A(0); sync
    stage(0); stage(1);
    bgA[0] = *(const bf16x8*)(pBg0);  bgA[1] = *(const bf16x8*)(pBg1);
    boA[0] = *(const bf16x8*)(pBo0);  boA[1] = *(const bf16x8*)(pBo1);
    asm volatile("s_waitcnt vmcnt(6)" ::: "memory");   // retire A(0) stage
    BAR();

    auto body = [&](int t, bf16x8 (&bgc)[2], bf16x8 (&boc)[2],
                    bf16x8 (&bgn)[2], bf16x8 (&bon)[2]) {
        // ds_reads A(t) (ready: retired+barrier'd in body(t-1))
        const char* bufA = smem + (t & 3) * 16384 + baseA;
        bf16x8 af[8];
        #pragma unroll
        for (int i = 0; i < 8; ++i) af[i] = *(const bf16x8*)(bufA + i * 1024);
        // B(t+1) -> regs (VMEM, retired at body(t+1)'s vmcnt)
        if (t + 1 < NK) {
            int kk = (t + 1) * 64;
            bgn[0] = *(const bf16x8*)(pBg0 + kk);  bgn[1] = *(const bf16x8*)(pBg1 + kk);
            bon[0] = *(const bf16x8*)(pBo0 + kk);  bon[1] = *(const bf16x8*)(pBo1 + kk);
        }
        // stage A(t+2)
        if (t + 2 < NK) stage(t + 2);
        // retire everything older than this body's issues
        if (t + 2 < NK)      { asm volatile("s_waitcnt vmcnt(6)" ::: "memory"); }
        else if (t + 1 < NK) { asm volatile("s_waitcnt vmcnt(4)" ::: "memory"); }
        else                 { asm volatile("s_waitcnt vmcnt(0)" ::: "memory"); }
        BAR();
        __builtin_amdgcn_s_setprio(1);
        #pragma unroll
        for (int fm = 0; fm < 8; ++fm)
            #pragma unroll
            for (int fn = 0; fn < 2; ++fn) {
                ag[fm][fn] = MFMA16(bgc[fn], af[fm], ag[fm][fn]);
                ao[fm][fn] = MFMA16(boc[fn], af[fm], ao[fm][fn]);
            }
        __builtin_amdgcn_s_setprio(0);
    };

    #pragma unroll 1
    for (int t = 0; t < NK; t += 2) {
        body(t, bgA, boA, bgB, boB);
        body(t + 1, bgB, boB, bgA, boA);
    }

    // epilogue: silu(g)*o, packed 8B bf16 stores
    u16* He = Hb + (size_t)e * GC * HDIM;
    int row0 = mt * 256 + wm * 128 + fr;
    int col0 = nt * 128 + wn * 32 + fg * 4;
    #pragma unroll
    for (int fm = 0; fm < 8; ++fm)
        #pragma unroll
        for (int fn = 0; fn < 2; ++fn) {
            s16x4 pk;
            #pragma unroll
            for (int r = 0; r < 4; ++r) {
                float gv = ag[fm][fn][r], ov = ao[fm][fn][r];
                float hv = gv / (1.f + __expf(-gv)) * ov;
                pk[r] = (short)f2bf(hv);
            }
            *(s16x4*)(He + (size_t)(row0 + fm * 16) * HDIM + col0 + fn * 16) = pk;
        }
}

// ======================================================================
// GEMM3: BM=128 BN=256 BK=32. A in ring-4 LDS (32 KiB), B (Wo) global->reg
// dbuf'd (4 frags/wave). One barrier/tile, counted vmcnt.
// ======================================================================
__global__ __launch_bounds__(512, 1) void gemm_out_v8(
        const u16* __restrict__ Hb, const u16* __restrict__ WoT,
        float* __restrict__ EO) {
    extern __shared__ char smem[];
    const int NK = HDIM / 32;                      // 128
    int bid = blockIdx.x;
    int swz = (bid & 7) * 80 + (bid >> 3);         // bijective (640 % 8 == 0)
    int nt = swz & 3, mt = (swz / 4) % 20, e = swz / 80;
    const char* A = (const char*)(Hb  + (size_t)e * GC * HDIM   + (size_t)mt * 128 * HDIM);
    const char* B = (const char*)(WoT + (size_t)e * MDIM * HDIM + (size_t)nt * 256 * HDIM);
    int tid = threadIdx.x, w = tid >> 6, l = tid & 63;
    int wm = w >> 2, wn = w & 3;
    int rl = l >> 2, cch = (l & 3) * 16;
    int fr = l & 15, fg = l >> 4;
    int lswz = ((fr >> 1) & 3) << 4;

    int rA = w * 16 + rl;
    const char* gA = A + (size_t)rA * HDIM * 2 + (cch ^ swzb(rA));
    int baseA = (wm * 64 + fr) * 64 + ((fg * 16) ^ lswz);

    const char* pB0 = B + (size_t)(wn * 64 + 0 * 16 + fr) * HDIM * 2 + fg * 16;
    const char* pB1 = B + (size_t)(wn * 64 + 1 * 16 + fr) * HDIM * 2 + fg * 16;
    const char* pB2 = B + (size_t)(wn * 64 + 2 * 16 + fr) * HDIM * 2 + fg * 16;
    const char* pB3 = B + (size_t)(wn * 64 + 3 * 16 + fr) * HDIM * 2 + fg * 16;

    f32x4 acc[4][4];
    #pragma unroll
    for (int i = 0; i < 4; ++i)
        #pragma unroll
        for (int j = 0; j < 4; ++j) acc[i][j] = (f32x4){0,0,0,0};

    auto stage = [&](int tt) {                     // 1 gload (A only)
        int kk = tt * 64, b = tt & 3;
        gload16(gA + kk, smem + b * 8192 + w * 1024);
    };

    bf16x8 bA[4], bB[4];

    stage(0); stage(1);
    bA[0] = *(const bf16x8*)(pB0);  bA[1] = *(const bf16x8*)(pB1);
    bA[2] = *(const bf16x8*)(pB2);  bA[3] = *(const bf16x8*)(pB3);
    asm volatile("s_waitcnt vmcnt(5)" ::: "memory");   // retire A(0) stage
    BAR();

    auto body = [&](int t, bf16x8 (&bc)[4], bf16x8 (&bn)[4]) {
        const char* pA = smem + (t & 3) * 8192 + baseA;
        bf16x8 af[4];
        #pragma unroll
        for (int i = 0; i < 4; ++i) af[i] = *(const bf16x8*)(pA + i * 1024);
        if (t + 1 < NK) {
            int kk = (t + 1) * 64;
            bn[0] = *(const bf16x8*)(pB0 + kk);  bn[1] = *(const bf16x8*)(pB1 + kk);
            bn[2] = *(const bf16x8*)(pB2 + kk);  bn[3] = *(const bf16x8*)(pB3 + kk);
        }
        if (t + 2 < NK) stage(t + 2);
        if (t + 2 < NK)      { asm volatile("s_waitcnt vmcnt(5)" ::: "memory"); }
        else if (t + 1 < NK) { asm volatile("s_waitcnt vmcnt(4)" ::: "memory"); }
        else                 { asm volatile("s_waitcnt vmcnt(0)" ::: "memory"); }
        BAR();
        __builtin_amdgcn_s_setprio(1);
        #pragma unroll
        for (int fm = 0; fm < 4; ++fm)
            #pragma unroll
            for (int fn = 0; fn < 4; ++fn)
                acc[fm][fn] = MFMA16(bc[fn], af[fm], acc[fm][fn]);
        __builtin_amdgcn_s_setprio(0);
    };

    #pragma unroll 1
    for (int t = 0; t < NK; t += 2) {
        body(t, bA, bB);
        body(t + 1, bB, bA);
    }

    float* Ee = EO + (size_t)e * GC * MDIM;
    int row0 = mt * 128 + wm * 64 + fr;
    int col0 = nt * 256 + wn * 64 + fg * 4;
    #pragma unroll
    for (int fm = 0; fm < 4; ++fm)
        #pragma unroll
        for (int fn = 0; fn < 4; ++fn)
            *(f32x4*)(Ee + (size_t)(row0 + fm * 16) * MDIM + col0 + fn * 16) = acc[fm][fn];
}

// ---------------- combine ----------------
__global__ __launch_bounds__(256) void combine_kernel(const float* __restrict__ EO,
                                                      const int* __restrict__ top_i,
                                                      const float* __restrict__ top_p,
                                                      const int* __restrict__ token_c,
                                                      float* __restrict__ out) {
    int tok = blockIdx.x, t = threadIdx.x;
    int g = tok >> 11;
    f32x4 acc = {0.f, 0.f, 0.f, 0.f};
    #pragma unroll
    for (int k = 0; k < 2; ++k) {
        int c = token_c[tok * 2 + k];
        if (c >= 0) {
            int e = top_i[tok * 2 + k];
            float p = top_p[tok * 2 + k];
            const float* src = EO + ((size_t)e * GC + g * CAP + c) * MDIM + t * 4;
            f32x4 v = *(const f32x4*)src;
            #pragma unroll
            for (int j = 0; j < 4; ++j) acc[j] += p * v[j];
        }
    }
    *(f32x4*)(out + (size_t)tok * MDIM + t * 4) = acc;
}

extern "C" void kernel_launch(void* const* d_in, const int* in_sizes, int n_in,
                              void* d_out, int out_size, void* d_ws, size_t ws_size,
                              hipStream_t stream) {
    (void)in_sizes; (void)n_in; (void)out_size; (void)ws_size;
    const float* inputs   = (const float*)d_in[0];
    const float* paddings = (const float*)d_in[1];
    const float* router_w = (const float*)d_in[2];
    const float* wi_gate  = (const float*)d_in[3];
    const float* wi_0     = (const float*)d_in[4];
    const float* wo       = (const float*)d_in[5];
    float* out = (float*)d_out;

    char* p = (char*)d_ws;
    u16* WgT = (u16*)p; p += (size_t)E * HDIM * MDIM * 2;
    u16* W0T = (u16*)p; p += (size_t)E * HDIM * MDIM * 2;
    u16* WoT = (u16*)p; p += (size_t)E * HDIM * MDIM * 2;
    u16* Xb  = (u16*)p; p += (size_t)E * GC * MDIM * 2;
    u16* Hb  = (u16*)p; p += (size_t)E * GC * HDIM * 2;
    float* EO = (float*)p; p += (size_t)E * GC * MDIM * 4;
    int*   top_i = (int*)p;   p += (size_t)G * S * TOPK * 4;
    float* top_p = (float*)p; p += (size_t)G * S * TOPK * 4;
    int*   token_c = (int*)p; p += (size_t)G * S * TOPK * 4;
    int*   slot_token = (int*)p; p += (size_t)E * G * CAP * 4;
    float* partials = (float*)p; p += (size_t)4096 * 17 * 4;
    float* sums = (float*)p; p += 4 * 17 * 4;

    hipMemsetAsync(token_c, 0xFF, (size_t)G * S * TOPK * 4, stream);
    hipMemsetAsync(slot_token, 0xFF, (size_t)E * G * CAP * 4, stream);

    hipFuncSetAttribute((const void*)gemm_ffn12_v8,
                        hipFuncAttributeMaxDynamicSharedMemorySize, 65536);
    hipFuncSetAttribute((const void*)gemm_out_v8,
                        hipFuncAttributeMaxDynamicSharedMemorySize, 32768);

    transpose_cvt<<<dim3(HDIM/64, MDIM/64, E), 256, 0, stream>>>(wi_gate, WgT, MDIM, HDIM);
    transpose_cvt<<<dim3(HDIM/64, MDIM/64, E), 256, 0, stream>>>(wi_0,   W0T, MDIM, HDIM);
    transpose_cvt<<<dim3(MDIM/64, HDIM/64, E), 256, 0, stream>>>(wo,     WoT, HDIM, MDIM);

    router_kernel<<<G * S / 4, 256, 0, stream>>>(inputs, router_w, top_i, top_p, partials);
    reduce_partials<<<G, 256, 0, stream>>>(partials, sums);
    scan_kernel<<<G * E, 256, 0, stream>>>(top_i, paddings, slot_token, token_c);
    gather_kernel<<<E * GC, 128, 0, stream>>>(inputs, slot_token, Xb);
    gemm_ffn12_v8<<<2560, 512, 65536, stream>>>(Xb, WgT, W0T, Hb);
    gemm_out_v8<<<640, 512, 32768, stream>>>(Hb, WoT, EO);
    combine_kernel<<<G * S, 256, 0, stream>>>(EO, top_i, top_p, token_c, out);
    aux_final<<<1, 1, 0, stream>>>(sums, out);
}

// Round 9
// 787.664 us; speedup vs baseline: 1.3424x; 1.3424x over previous
//
#include <hip/hip_runtime.h>
#include <hip/hip_bf16.h>
#include <math.h>

#define G 4
#define S 2048
#define MDIM 1024
#define E 8
#define HDIM 4096
#define TOPK 2
#define CAP 640
#define GC (G*CAP)      /* 2560 rows per expert */

typedef __attribute__((ext_vector_type(8))) short bf16x8;
typedef __attribute__((ext_vector_type(4))) short s16x4;
typedef __attribute__((ext_vector_type(4))) float f32x4;
typedef __attribute__((ext_vector_type(16))) float f32x16;
typedef unsigned int u32;
typedef unsigned short u16;

#define MFMA32(a,b,c) __builtin_amdgcn_mfma_f32_32x32x16_bf16(a,b,c,0,0,0)
#define BAR() __builtin_amdgcn_s_barrier()

__device__ __forceinline__ u16 f2bf(float f) {
    union { float f; u32 u; } v; v.f = f;
    u32 r = v.u + 0x7fffu + ((v.u >> 16) & 1u);
    return (u16)(r >> 16);
}

__device__ __forceinline__ void gload16(const char* gp, char* lp) {
    __builtin_amdgcn_global_load_lds((const __attribute__((address_space(1))) u32*)gp,
                                     (__attribute__((address_space(3))) u32*)lp,
                                     16, 0, 0);
}

// 3-bit XOR swizzle for 128-byte LDS rows (BK=64 bf16): spreads rows across
// the 8 16B slots. Involution; applied to global SOURCE + LDS READ (rule 21).
__device__ __forceinline__ int swz128(int r) { return ((r >> 1) & 7) << 4; }

// ---------------- weight transpose + f32->bf16 convert (64x64, R5-proven) ----
__global__ __launch_bounds__(256) void transpose_cvt(const float* __restrict__ in,
                                                     u16* __restrict__ out, int R, int C) {
    int e = blockIdx.z;
    const float* ine = in + (size_t)e * R * C;
    u16* oute = out + (size_t)e * R * C;
    __shared__ float tile[64][68];
    int t = threadIdx.x;
    int x0 = blockIdx.x * 64, y0 = blockIdx.y * 64;
    int lx = (t & 15) * 4, ly = t >> 4;
    #pragma unroll
    for (int i = 0; i < 4; ++i) {
        f32x4 v = *(const f32x4*)(ine + (size_t)(y0 + ly + i * 16) * C + x0 + lx);
        *(f32x4*)&tile[ly + i * 16][lx] = v;
    }
    __syncthreads();
    int rr0 = (t & 15) * 4, cb = t >> 4;
    #pragma unroll
    for (int p = 0; p < 4; ++p) {
        int cc = cb + p * 16;
        s16x4 pk;
        #pragma unroll
        for (int j = 0; j < 4; ++j) pk[j] = (short)f2bf(tile[rr0 + j][cc]);
        *(s16x4*)(oute + (size_t)(x0 + cc) * R + y0 + rr0) = pk;
    }
}

// ---------------- router ----------------
__global__ __launch_bounds__(256) void router_kernel(const float* __restrict__ inp,
                                                     const float* __restrict__ rw,
                                                     int* __restrict__ top_i,
                                                     float* __restrict__ top_p,
                                                     float* __restrict__ partials) {
    int wid = threadIdx.x >> 6, lane = threadIdx.x & 63;
    int tok = blockIdx.x * 4 + wid;
    const float* x = inp + (size_t)tok * MDIM;
    float acc[E] = {0.f,0.f,0.f,0.f,0.f,0.f,0.f,0.f};
    #pragma unroll
    for (int rep = 0; rep < 4; ++rep) {
        int m0 = rep * 256 + lane * 4;
        f32x4 xv = *(const f32x4*)(x + m0);
        #pragma unroll
        for (int j = 0; j < 4; ++j) {
            const float* r = rw + (size_t)(m0 + j) * E;
            float xj = xv[j];
            #pragma unroll
            for (int e = 0; e < E; ++e) acc[e] += xj * r[e];
        }
    }
    #pragma unroll
    for (int e = 0; e < E; ++e)
        #pragma unroll
        for (int off = 32; off; off >>= 1) acc[e] += __shfl_down(acc[e], off);

    __shared__ float part[4][17];
    if (lane == 0) {
        float mx = acc[0];
        #pragma unroll
        for (int e = 1; e < E; ++e) mx = fmaxf(mx, acc[e]);
        float p[E], sum = 0.f;
        #pragma unroll
        for (int e = 0; e < E; ++e) { p[e] = expf(acc[e] - mx); sum += p[e]; }
        float inv = 1.f / sum;
        #pragma unroll
        for (int e = 0; e < E; ++e) p[e] *= inv;
        float lse = logf(sum) + mx;
        int i0 = 0;
        #pragma unroll
        for (int e = 1; e < E; ++e) if (acc[e] > acc[i0]) i0 = e;
        int i1 = (i0 == 0) ? 1 : 0;
        #pragma unroll
        for (int e = 0; e < E; ++e) if (e != i0 && acc[e] > acc[i1]) i1 = e;
        top_i[tok*2+0] = i0; top_i[tok*2+1] = i1;
        top_p[tok*2+0] = p[i0]; top_p[tok*2+1] = p[i1];
        #pragma unroll
        for (int e = 0; e < E; ++e) { part[wid][e] = p[e]; part[wid][8+e] = 0.f; }
        part[wid][8+i0] = 1.f; part[wid][8+i1] = 1.f;
        part[wid][16] = lse * lse;
    }
    __syncthreads();
    if (threadIdx.x < 17) {
        float v = part[0][threadIdx.x] + part[1][threadIdx.x] +
                  part[2][threadIdx.x] + part[3][threadIdx.x];
        partials[(size_t)blockIdx.x * 17 + threadIdx.x] = v;
    }
}

__global__ __launch_bounds__(256) void reduce_partials(const float* __restrict__ partials,
                                                       float* __restrict__ sums) {
    int g = blockIdx.x, t = threadIdx.x;
    float loc[17];
    #pragma unroll
    for (int c = 0; c < 17; ++c) loc[c] = 0.f;
    for (int r = t; r < 1024; r += 256) {
        const float* pr = partials + ((size_t)g * 1024 + r) * 17;
        #pragma unroll
        for (int c = 0; c < 17; ++c) loc[c] += pr[c];
    }
    __shared__ float red[256];
    for (int c = 0; c < 17; ++c) {
        red[t] = loc[c]; __syncthreads();
        for (int off = 128; off; off >>= 1) {
            if (t < off) red[t] += red[t + off];
            __syncthreads();
        }
        if (t == 0) sums[g * 17 + c] = red[0];
        __syncthreads();
    }
}

__global__ void aux_final(const float* __restrict__ sums, float* __restrict__ out) {
    float lb = 0.f, z = 0.f;
    for (int g = 0; g < G; ++g) {
        for (int e = 0; e < E; ++e)
            lb += (sums[g*17 + 8 + e] / (float)S) * (sums[g*17 + e] / (float)S);
        z += sums[g*17 + 16];
    }
    lb = lb / (float)(G * E) * (float)(E * E);
    z /= (float)(G * S);
    out[(size_t)G * S * MDIM] = 0.01f * lb + 0.001f * z;
}

// ---------------- capacity scan ----------------
__global__ __launch_bounds__(256) void scan_kernel(const int* __restrict__ top_i,
                                                   const float* __restrict__ pad,
                                                   int* __restrict__ slot_token,
                                                   int* __restrict__ token_c) {
    int b = blockIdx.x; int g = b >> 3, e = b & 7;
    int t = threadIdx.x;
    __shared__ int sums[256];
    int base = t * 16;
    int run = 0; unsigned mask16 = 0; int loc[16];
    #pragma unroll
    for (int j = 0; j < 16; ++j) {
        int i = base + j; int s = i >> 1, k = i & 1;
        int ex = top_i[((size_t)(g * S + s)) * 2 + k];
        int m = (ex == e) && (pad[g * S + s] == 0.f);
        run += m; loc[j] = run; mask16 |= ((unsigned)m << j);
    }
    sums[t] = run; __syncthreads();
    for (int off = 1; off < 256; off <<= 1) {
        int v = (t >= off) ? sums[t - off] : 0;
        __syncthreads();
        sums[t] += v;
        __syncthreads();
    }
    int excl = sums[t] - run;
    #pragma unroll
    for (int j = 0; j < 16; ++j) {
        if ((mask16 >> j) & 1u) {
            int pos = excl + loc[j];
            if (pos <= CAP) {
                int i = base + j; int s = i >> 1, k = i & 1;
                slot_token[((size_t)(e * G + g)) * CAP + (pos - 1)] = s;
                token_c[((size_t)(g * S + s)) * 2 + k] = pos - 1;
            }
        }
    }
}

// ---------------- gather tokens -> X bf16 [E][GC][MDIM] ----------------
__global__ __launch_bounds__(128) void gather_kernel(const float* __restrict__ inp,
                                                     const int* __restrict__ slot_token,
                                                     u16* __restrict__ X) {
    int row = blockIdx.x;
    int t = threadIdx.x;
    int s = slot_token[row];
    int g = (row % GC) / CAP;
    bf16x8 v;
    if (s >= 0) {
        const float* src = inp + ((size_t)(g * S + s)) * MDIM + t * 8;
        f32x4 a = *(const f32x4*)src;
        f32x4 b = *(const f32x4*)(src + 4);
        #pragma unroll
        for (int j = 0; j < 4; ++j) { v[j] = (short)f2bf(a[j]); v[4+j] = (short)f2bf(b[j]); }
    } else {
        #pragma unroll
        for (int j = 0; j < 8; ++j) v[j] = 0;
    }
    *(bf16x8*)(X + (size_t)row * MDIM + t * 8) = v;
}

// ======================================================================
// GEMM1+2 fused, 32x32x16 MFMA, BM=256 BN=128 BK=64, ring-2 LDS 128KiB.
// Waves 2Mx4N; wave = 128 rows x 32 cols, dual-B. Per K-tile: 32 MFMA +
// 24 ds_read_b128 per wave (half the instr count of the 16x16 version).
// stage(t+1) overlaps compute(t); vmcnt(0)+barrier once per K=64.
// LDS buf: A 32K @0, Bg 16K @32768, B0 16K @49152  (x2 dbuf).
// ======================================================================
__global__ __launch_bounds__(512, 1) void gemm_ffn12_v9(
        const u16* __restrict__ Xb, const u16* __restrict__ WgT,
        const u16* __restrict__ W0T, u16* __restrict__ Hb) {
    extern __shared__ char smem[];
    const int NK = MDIM / 64;                      // 16
    int bid = blockIdx.x;
    int swz = (bid & 7) * 320 + (bid >> 3);        // bijective (2560 % 8 == 0)
    int mt = swz % 10, nt = (swz / 10) & 31, e = swz / 320;
    const char* A  = (const char*)(Xb  + (size_t)e * GC * MDIM   + (size_t)mt * 256 * MDIM);
    const char* Bg = (const char*)(WgT + (size_t)e * HDIM * MDIM + (size_t)nt * 128 * MDIM);
    const char* B0 = (const char*)(W0T + (size_t)e * HDIM * MDIM + (size_t)nt * 128 * MDIM);
    int tid = threadIdx.x, w = tid >> 6, l = tid & 63;
    int wm = w >> 2, wn = w & 3;                   // 2M x 4N waves
    int lr = l & 31, lk = l >> 5;                  // frag: row-in-32, k-half
    int lswz = ((lr >> 1) & 7) << 4;

    // per-lane read offsets: ks quarter -> byte (ks*32 + lk*16) ^ lswz
    int koff[4];
    #pragma unroll
    for (int ks = 0; ks < 4; ++ks) koff[ks] = (ks * 32 + lk * 16) ^ lswz;
    int baseA[4];
    #pragma unroll
    for (int rb = 0; rb < 4; ++rb) baseA[rb] = (wm * 128 + rb * 32 + lr) * 128;
    int baseB = (wn * 32 + lr) * 128;

    // staging source pointers (pass p covers rows p*64 + w*8 + (l>>3))
    const char* srcA[4]; const char* srcG[2]; const char* srcO[2];
    #pragma unroll
    for (int p = 0; p < 4; ++p) {
        int gr = p * 64 + w * 8 + (l >> 3);
        srcA[p] = A + (size_t)gr * (MDIM * 2) + (((l & 7) * 16) ^ swz128(gr));
    }
    #pragma unroll
    for (int p = 0; p < 2; ++p) {
        int gr = p * 64 + w * 8 + (l >> 3);
        srcG[p] = Bg + (size_t)gr * (MDIM * 2) + (((l & 7) * 16) ^ swz128(gr));
        srcO[p] = B0 + (size_t)gr * (MDIM * 2) + (((l & 7) * 16) ^ swz128(gr));
    }

    f32x16 zz;
    #pragma unroll
    for (int i = 0; i < 16; ++i) zz[i] = 0.f;
    f32x16 ag[4], ao[4];
    #pragma unroll
    for (int rb = 0; rb < 4; ++rb) { ag[rb] = zz; ao[rb] = zz; }

    auto stage = [&](int tt) {                     // 8 gloads per thread
        int kk = tt * 128;
        char* dst = smem + (tt & 1) * 65536;
        #pragma unroll
        for (int p = 0; p < 4; ++p)
            gload16(srcA[p] + kk, dst + (p * 64 + w * 8) * 128);
        #pragma unroll
        for (int p = 0; p < 2; ++p) {
            gload16(srcG[p] + kk, dst + 32768 + (p * 64 + w * 8) * 128);
            gload16(srcO[p] + kk, dst + 49152 + (p * 64 + w * 8) * 128);
        }
    };

    stage(0);
    asm volatile("s_waitcnt vmcnt(0)" ::: "memory");
    BAR();

    #pragma unroll 1
    for (int t = 0; t < NK; ++t) {
        if (t + 1 < NK) stage(t + 1);
        const char* bufc = smem + (t & 1) * 65536;
        #pragma unroll
        for (int ks = 0; ks < 4; ++ks) {
            bf16x8 bg = *(const bf16x8*)(bufc + 32768 + baseB + koff[ks]);
            bf16x8 bo = *(const bf16x8*)(bufc + 49152 + baseB + koff[ks]);
            bf16x8 af[4];
            #pragma unroll
            for (int rb = 0; rb < 4; ++rb)
                af[rb] = *(const bf16x8*)(bufc + baseA[rb] + koff[ks]);
            __builtin_amdgcn_s_setprio(1);
            #pragma unroll
            for (int rb = 0; rb < 4; ++rb) {
                ag[rb] = MFMA32(bg, af[rb], ag[rb]);
                ao[rb] = MFMA32(bo, af[rb], ao[rb]);
            }
            __builtin_amdgcn_s_setprio(0);
        }
        asm volatile("s_waitcnt vmcnt(0)" ::: "memory");
        BAR();
    }

    // epilogue: silu(g)*o, packed 8B stores; lane holds rows lr(+rb*32),
    // cols col0 + q*8 + {0..3} (reg-quad = 4 consecutive cols)
    u16* He = Hb + (size_t)e * GC * HDIM;
    int row0 = mt * 256 + wm * 128 + lr;
    int col0 = nt * 128 + wn * 32 + lk * 4;
    #pragma unroll
    for (int rb = 0; rb < 4; ++rb) {
        size_t rowoff = (size_t)(row0 + rb * 32) * HDIM;
        #pragma unroll
        for (int q = 0; q < 4; ++q) {
            s16x4 pk;
            #pragma unroll
            for (int r = 0; r < 4; ++r) {
                float gv = ag[rb][q * 4 + r], ov = ao[rb][q * 4 + r];
                float hv = gv / (1.f + __expf(-gv)) * ov;
                pk[r] = (short)f2bf(hv);
            }
            *(s16x4*)(He + rowoff + col0 + q * 8) = pk;
        }
    }
}

// ======================================================================
// GEMM3, 32x32x16 MFMA, BM=128 BN=256 BK=64, ring-2 LDS 96KiB.
// Waves 2Mx4N; wave = 64 rows x 64 cols. Per K-tile: 16 MFMA + 16 reads.
// LDS buf: A 16K @0, B 32K @16384  (x2 dbuf).
// ======================================================================
__global__ __launch_bounds__(512, 1) void gemm_out_v9(
        const u16* __restrict__ Hb, const u16* __restrict__ WoT,
        float* __restrict__ EO) {
    extern __shared__ char smem[];
    const int NK = HDIM / 64;                      // 64
    int bid = blockIdx.x;
    int swz = (bid & 7) * 80 + (bid >> 3);         // bijective (640 % 8 == 0)
    int nt = swz & 3, mt = (swz / 4) % 20, e = swz / 80;
    const char* A = (const char*)(Hb  + (size_t)e * GC * HDIM   + (size_t)mt * 128 * HDIM);
    const char* B = (const char*)(WoT + (size_t)e * MDIM * HDIM + (size_t)nt * 256 * HDIM);
    int tid = threadIdx.x, w = tid >> 6, l = tid & 63;
    int wm = w >> 2, wn = w & 3;
    int lr = l & 31, lk = l >> 5;
    int lswz = ((lr >> 1) & 7) << 4;

    int koff[4];
    #pragma unroll
    for (int ks = 0; ks < 4; ++ks) koff[ks] = (ks * 32 + lk * 16) ^ lswz;
    int baseA[2], baseB[2];
    #pragma unroll
    for (int rb = 0; rb < 2; ++rb) baseA[rb] = (wm * 64 + rb * 32 + lr) * 128;
    #pragma unroll
    for (int cb = 0; cb < 2; ++cb) baseB[cb] = (wn * 64 + cb * 32 + lr) * 128;

    const char* srcA[2]; const char* srcB[4];
    #pragma unroll
    for (int p = 0; p < 2; ++p) {
        int gr = p * 64 + w * 8 + (l >> 3);
        srcA[p] = A + (size_t)gr * (HDIM * 2) + (((l & 7) * 16) ^ swz128(gr));
    }
    #pragma unroll
    for (int p = 0; p < 4; ++p) {
        int gr = p * 64 + w * 8 + (l >> 3);
        srcB[p] = B + (size_t)gr * (HDIM * 2) + (((l & 7) * 16) ^ swz128(gr));
    }

    f32x16 zz;
    #pragma unroll
    for (int i = 0; i < 16; ++i) zz[i] = 0.f;
    f32x16 acc[2][2];
    #pragma unroll
    for (int i = 0; i < 2; ++i)
        #pragma unroll
        for (int j = 0; j < 2; ++j) acc[i][j] = zz;

    auto stage = [&](int tt) {                     // 6 gloads per thread
        int kk = tt * 128;
        char* dst = smem + (tt & 1) * 49152;
        #pragma unroll
        for (int p = 0; p < 2; ++p)
            gload16(srcA[p] + kk, dst + (p * 64 + w * 8) * 128);
        #pragma unroll
        for (int p = 0; p < 4; ++p)
            gload16(srcB[p] + kk, dst + 16384 + (p * 64 + w * 8) * 128);
    };

    stage(0);
    asm volatile("s_waitcnt vmcnt(0)" ::: "memory");
    BAR();

    #pragma unroll 1
    for (int t = 0; t < NK; ++t) {
        if (t + 1 < NK) stage(t + 1);
        const char* bufc = smem + (t & 1) * 49152;
        #pragma unroll
        for (int ks = 0; ks < 4; ++ks) {
            bf16x8 bf[2], af[2];
            #pragma unroll
            for (int cb = 0; cb < 2; ++cb)
                bf[cb] = *(const bf16x8*)(bufc + 16384 + baseB[cb] + koff[ks]);
            #pragma unroll
            for (int rb = 0; rb < 2; ++rb)
                af[rb] = *(const bf16x8*)(bufc + baseA[rb] + koff[ks]);
            __builtin_amdgcn_s_setprio(1);
            #pragma unroll
            for (int rb = 0; rb < 2; ++rb)
                #pragma unroll
                for (int cb = 0; cb < 2; ++cb)
                    acc[rb][cb] = MFMA32(bf[cb], af[rb], acc[rb][cb]);
            __builtin_amdgcn_s_setprio(0);
        }
        asm volatile("s_waitcnt vmcnt(0)" ::: "memory");
        BAR();
    }

    float* Ee = EO + (size_t)e * GC * MDIM;
    int row0 = mt * 128 + wm * 64 + lr;
    int col0 = nt * 256 + wn * 64 + lk * 4;
    #pragma unroll
    for (int rb = 0; rb < 2; ++rb) {
        size_t rowoff = (size_t)(row0 + rb * 32) * MDIM;
        #pragma unroll
        for (int cb = 0; cb < 2; ++cb)
            #pragma unroll
            for (int q = 0; q < 4; ++q) {
                f32x4 v;
                #pragma unroll
                for (int r = 0; r < 4; ++r) v[r] = acc[rb][cb][q * 4 + r];
                *(f32x4*)(Ee + rowoff + col0 + cb * 32 + q * 8) = v;
            }
    }
}

// ---------------- combine ----------------
__global__ __launch_bounds__(256) void combine_kernel(const float* __restrict__ EO,
                                                      const int* __restrict__ top_i,
                                                      const float* __restrict__ top_p,
                                                      const int* __restrict__ token_c,
                                                      float* __restrict__ out) {
    int tok = blockIdx.x, t = threadIdx.x;
    int g = tok >> 11;
    f32x4 acc = {0.f, 0.f, 0.f, 0.f};
    #pragma unroll
    for (int k = 0; k < 2; ++k) {
        int c = token_c[tok * 2 + k];
        if (c >= 0) {
            int e = top_i[tok * 2 + k];
            float p = top_p[tok * 2 + k];
            const float* src = EO + ((size_t)e * GC + g * CAP + c) * MDIM + t * 4;
            f32x4 v = *(const f32x4*)src;
            #pragma unroll
            for (int j = 0; j < 4; ++j) acc[j] += p * v[j];
        }
    }
    *(f32x4*)(out + (size_t)tok * MDIM + t * 4) = acc;
}

extern "C" void kernel_launch(void* const* d_in, const int* in_sizes, int n_in,
                              void* d_out, int out_size, void* d_ws, size_t ws_size,
                              hipStream_t stream) {
    (void)in_sizes; (void)n_in; (void)out_size; (void)ws_size;
    const float* inputs   = (const float*)d_in[0];
    const float* paddings = (const float*)d_in[1];
    const float* router_w = (const float*)d_in[2];
    const float* wi_gate  = (const float*)d_in[3];
    const float* wi_0     = (const float*)d_in[4];
    const float* wo       = (const float*)d_in[5];
    float* out = (float*)d_out;

    char* p = (char*)d_ws;
    u16* WgT = (u16*)p; p += (size_t)E * HDIM * MDIM * 2;
    u16* W0T = (u16*)p; p += (size_t)E * HDIM * MDIM * 2;
    u16* WoT = (u16*)p; p += (size_t)E * HDIM * MDIM * 2;
    u16* Xb  = (u16*)p; p += (size_t)E * GC * MDIM * 2;
    u16* Hb  = (u16*)p; p += (size_t)E * GC * HDIM * 2;
    float* EO = (float*)p; p += (size_t)E * GC * MDIM * 4;
    int*   top_i = (int*)p;   p += (size_t)G * S * TOPK * 4;
    float* top_p = (float*)p; p += (size_t)G * S * TOPK * 4;
    int*   token_c = (int*)p; p += (size_t)G * S * TOPK * 4;
    int*   slot_token = (int*)p; p += (size_t)E * G * CAP * 4;
    float* partials = (float*)p; p += (size_t)4096 * 17 * 4;
    float* sums = (float*)p; p += 4 * 17 * 4;

    hipMemsetAsync(token_c, 0xFF, (size_t)G * S * TOPK * 4, stream);
    hipMemsetAsync(slot_token, 0xFF, (size_t)E * G * CAP * 4, stream);

    hipFuncSetAttribute((const void*)gemm_ffn12_v9,
                        hipFuncAttributeMaxDynamicSharedMemorySize, 131072);
    hipFuncSetAttribute((const void*)gemm_out_v9,
                        hipFuncAttributeMaxDynamicSharedMemorySize, 98304);

    transpose_cvt<<<dim3(HDIM/64, MDIM/64, E), 256, 0, stream>>>(wi_gate, WgT, MDIM, HDIM);
    transpose_cvt<<<dim3(HDIM/64, MDIM/64, E), 256, 0, stream>>>(wi_0,   W0T, MDIM, HDIM);
    transpose_cvt<<<dim3(MDIM/64, HDIM/64, E), 256, 0, stream>>>(wo,     WoT, HDIM, MDIM);

    router_kernel<<<G * S / 4, 256, 0, stream>>>(inputs, router_w, top_i, top_p, partials);
    reduce_partials<<<G, 256, 0, stream>>>(partials, sums);
    scan_kernel<<<G * E, 256, 0, stream>>>(top_i, paddings, slot_token, token_c);
    gather_kernel<<<E * GC, 128, 0, stream>>>(inputs, slot_token, Xb);
    gemm_ffn12_v9<<<2560, 512, 131072, stream>>>(Xb, WgT, W0T, Hb);
    gemm_out_v9<<<640, 512, 98304, stream>>>(Hb, WoT, EO);
    combine_kernel<<<G * S, 256, 0, stream>>>(EO, top_i, top_p, token_c, out);
    aux_final<<<1, 1, 0, stream>>>(sums, out);
}

// Round 12
// 763.231 us; speedup vs baseline: 1.3854x; 1.0320x over previous
//
#include <hip/hip_runtime.h>
#include <hip/hip_bf16.h>
#include <math.h>

#define G 4
#define S 2048
#define MDIM 1024
#define E 8
#define HDIM 4096
#define TOPK 2
#define CAP 640
#define GC (G*CAP)      /* 2560 rows per expert */
#define RBLK (G*S/4)    /* 2048 router blocks, 4 tokens each */

typedef __attribute__((ext_vector_type(8))) short bf16x8;
typedef __attribute__((ext_vector_type(4))) short s16x4;
typedef __attribute__((ext_vector_type(4))) float f32x4;
typedef __attribute__((ext_vector_type(16))) float f32x16;
typedef unsigned int u32;
typedef unsigned short u16;

#define MFMA32(a,b,c) __builtin_amdgcn_mfma_f32_32x32x16_bf16(a,b,c,0,0,0)
#define BAR() __builtin_amdgcn_s_barrier()

__device__ __forceinline__ u16 f2bf(float f) {
    union { float f; u32 u; } v; v.f = f;
    u32 r = v.u + 0x7fffu + ((v.u >> 16) & 1u);
    return (u16)(r >> 16);
}

__device__ __forceinline__ void gload16(const char* gp, char* lp) {
    __builtin_amdgcn_global_load_lds((const __attribute__((address_space(1))) u32*)gp,
                                     (__attribute__((address_space(3))) u32*)lp,
                                     16, 0, 0);
}

// 3-bit XOR swizzle for 128-byte LDS rows (involution; source+read sides)
__device__ __forceinline__ int swz128(int r) { return ((r >> 1) & 7) << 4; }

// ============ fused prep: router (blocks 0..2047) + 3 transposes ============
__device__ void transpose_body(const float* __restrict__ in, u16* __restrict__ out,
                               int R, int C, int tb, float (*tile)[68]) {
    int nbx = C / 64, nby = R / 64;
    int bx = tb % nbx, by = (tb / nbx) % nby, e = tb / (nbx * nby);
    const float* ine = in + (size_t)e * R * C;
    u16* oute = out + (size_t)e * R * C;
    int t = threadIdx.x;
    int x0 = bx * 64, y0 = by * 64;
    int lx = (t & 15) * 4, ly = t >> 4;
    #pragma unroll
    for (int i = 0; i < 4; ++i) {
        f32x4 v = *(const f32x4*)(ine + (size_t)(y0 + ly + i * 16) * C + x0 + lx);
        *(f32x4*)&tile[ly + i * 16][lx] = v;
    }
    __syncthreads();
    int rr0 = (t & 15) * 4, cb = t >> 4;
    #pragma unroll
    for (int p = 0; p < 4; ++p) {
        int cc = cb + p * 16;
        s16x4 pk;
        #pragma unroll
        for (int j = 0; j < 4; ++j) pk[j] = (short)f2bf(tile[rr0 + j][cc]);
        *(s16x4*)(oute + (size_t)(x0 + cc) * R + y0 + rr0) = pk;
    }
}

__global__ __launch_bounds__(256) void prep_kernel(
        const float* __restrict__ inp, const float* __restrict__ rw,
        const float* __restrict__ wi_gate, const float* __restrict__ wi_0,
        const float* __restrict__ wo,
        u16* __restrict__ WgT, u16* __restrict__ W0T, u16* __restrict__ WoT,
        int* __restrict__ top_i, float* __restrict__ top_p,
        float* __restrict__ partials) {
    __shared__ float tile[64][68];
    __shared__ float part[4][17];
    int bid = blockIdx.x;
    if (bid >= RBLK) {                     // transposes: 3 x 8192 blocks
        int tb = bid - RBLK;
        if (tb < 8192)       transpose_body(wi_gate, WgT, MDIM, HDIM, tb, tile);
        else if (tb < 16384) transpose_body(wi_0,   W0T, MDIM, HDIM, tb - 8192, tile);
        else                 transpose_body(wo,     WoT, HDIM, MDIM, tb - 16384, tile);
        return;
    }
    // ---- router: 4 tokens per block, tokens 0..8191 ----
    int wid = threadIdx.x >> 6, lane = threadIdx.x & 63;
    int tok = bid * 4 + wid;
    const float* x = inp + (size_t)tok * MDIM;
    float acc[E] = {0.f,0.f,0.f,0.f,0.f,0.f,0.f,0.f};
    #pragma unroll
    for (int rep = 0; rep < 4; ++rep) {
        int m0 = rep * 256 + lane * 4;
        f32x4 xv = *(const f32x4*)(x + m0);
        #pragma unroll
        for (int j = 0; j < 4; ++j) {
            const float* r = rw + (size_t)(m0 + j) * E;
            float xj = xv[j];
            #pragma unroll
            for (int e = 0; e < E; ++e) acc[e] += xj * r[e];
        }
    }
    #pragma unroll
    for (int e = 0; e < E; ++e)
        #pragma unroll
        for (int off = 32; off; off >>= 1) acc[e] += __shfl_down(acc[e], off);

    if (lane == 0) {
        float mx = acc[0];
        #pragma unroll
        for (int e = 1; e < E; ++e) mx = fmaxf(mx, acc[e]);
        float p[E], sum = 0.f;
        #pragma unroll
        for (int e = 0; e < E; ++e) { p[e] = expf(acc[e] - mx); sum += p[e]; }
        float inv = 1.f / sum;
        #pragma unroll
        for (int e = 0; e < E; ++e) p[e] *= inv;
        float lse = logf(sum) + mx;
        int i0 = 0;
        #pragma unroll
        for (int e = 1; e < E; ++e) if (acc[e] > acc[i0]) i0 = e;
        int i1 = (i0 == 0) ? 1 : 0;
        #pragma unroll
        for (int e = 0; e < E; ++e) if (e != i0 && acc[e] > acc[i1]) i1 = e;
        top_i[tok*2+0] = i0; top_i[tok*2+1] = i1;
        top_p[tok*2+0] = p[i0]; top_p[tok*2+1] = p[i1];
        #pragma unroll
        for (int e = 0; e < E; ++e) { part[wid][e] = p[e]; part[wid][8+e] = 0.f; }
        part[wid][8+i0] = 1.f; part[wid][8+i1] = 1.f;
        part[wid][16] = lse * lse;
    }
    __syncthreads();
    if (threadIdx.x < 17) {
        float v = part[0][threadIdx.x] + part[1][threadIdx.x] +
                  part[2][threadIdx.x] + part[3][threadIdx.x];
        partials[(size_t)bid * 17 + threadIdx.x] = v;
    }
}

// ============ fused scan (blocks 0..31) + reduce_partials (32..35) ============
// partials layout: 512 blocks per group g at rows [g*512, (g+1)*512)
__global__ __launch_bounds__(256) void scan_reduce_kernel(
        const int* __restrict__ top_i, const float* __restrict__ pad,
        const float* __restrict__ partials,
        int* __restrict__ slot_token, int* __restrict__ token_c,
        float* __restrict__ sums_out) {
    __shared__ int sums[256];
    __shared__ float red[256];
    int bid = blockIdx.x;
    int t = threadIdx.x;
    if (bid >= 32) {
        int g = bid - 32;
        float loc[17];
        #pragma unroll
        for (int c = 0; c < 17; ++c) loc[c] = 0.f;
        for (int r = t; r < 512; r += 256) {          // 512 router blocks/group
            const float* pr = partials + ((size_t)g * 512 + r) * 17;
            #pragma unroll
            for (int c = 0; c < 17; ++c) loc[c] += pr[c];
        }
        for (int c = 0; c < 17; ++c) {
            red[t] = loc[c]; __syncthreads();
            for (int off = 128; off; off >>= 1) {
                if (t < off) red[t] += red[t + off];
                __syncthreads();
            }
            if (t == 0) sums_out[g * 17 + c] = red[0];
            __syncthreads();
        }
        return;
    }
    int g = bid >> 3, e = bid & 7;
    int base = t * 16;
    int run = 0; unsigned mask16 = 0; int loc[16];
    #pragma unroll
    for (int j = 0; j < 16; ++j) {
        int i = base + j; int s = i >> 1, k = i & 1;
        int ex = top_i[((size_t)(g * S + s)) * 2 + k];
        int m = (ex == e) && (pad[g * S + s] == 0.f);
        run += m; loc[j] = run; mask16 |= ((unsigned)m << j);
    }
    sums[t] = run; __syncthreads();
    for (int off = 1; off < 256; off <<= 1) {
        int v = (t >= off) ? sums[t - off] : 0;
        __syncthreads();
        sums[t] += v;
        __syncthreads();
    }
    int excl = sums[t] - run;
    #pragma unroll
    for (int j = 0; j < 16; ++j) {
        if ((mask16 >> j) & 1u) {
            int pos = excl + loc[j];
            if (pos <= CAP) {
                int i = base + j; int s = i >> 1, k = i & 1;
                slot_token[((size_t)(e * G + g)) * CAP + (pos - 1)] = s;
                token_c[((size_t)(g * S + s)) * 2 + k] = pos - 1;
            }
        }
    }
}

// ---------------- gather tokens -> X bf16 [E][GC][MDIM] ----------------
__global__ __launch_bounds__(128) void gather_kernel(const float* __restrict__ inp,
                                                     const int* __restrict__ slot_token,
                                                     u16* __restrict__ X) {
    int row = blockIdx.x;
    int t = threadIdx.x;
    int s = slot_token[row];
    int g = (row % GC) / CAP;
    bf16x8 v;
    if (s >= 0) {
        const float* src = inp + ((size_t)(g * S + s)) * MDIM + t * 8;
        f32x4 a = *(const f32x4*)src;
        f32x4 b = *(const f32x4*)(src + 4);
        #pragma unroll
        for (int j = 0; j < 4; ++j) { v[j] = (short)f2bf(a[j]); v[4+j] = (short)f2bf(b[j]); }
    } else {
        #pragma unroll
        for (int j = 0; j < 8; ++j) v[j] = 0;
    }
    *(bf16x8*)(X + (size_t)row * MDIM + t * 8) = v;
}

// ======================================================================
// GEMM1+2 fused (R9-proven, unchanged): 32x32x16, BM=256 BN=128 BK=64,
// ring-2 LDS 128KiB, stage(t+1) || compute(t), vmcnt(0)+barrier per tile.
// ======================================================================
__global__ __launch_bounds__(512, 1) void gemm_ffn12_v9(
        const u16* __restrict__ Xb, const u16* __restrict__ WgT,
        const u16* __restrict__ W0T, u16* __restrict__ Hb) {
    extern __shared__ char smem[];
    const int NK = MDIM / 64;                      // 16
    int bid = blockIdx.x;
    int swz = (bid & 7) * 320 + (bid >> 3);        // bijective (2560 % 8 == 0)
    int mt = swz % 10, nt = (swz / 10) & 31, e = swz / 320;
    const char* A  = (const char*)(Xb  + (size_t)e * GC * MDIM   + (size_t)mt * 256 * MDIM);
    const char* Bg = (const char*)(WgT + (size_t)e * HDIM * MDIM + (size_t)nt * 128 * MDIM);
    const char* B0 = (const char*)(W0T + (size_t)e * HDIM * MDIM + (size_t)nt * 128 * MDIM);
    int tid = threadIdx.x, w = tid >> 6, l = tid & 63;
    int wm = w >> 2, wn = w & 3;
    int lr = l & 31, lk = l >> 5;
    int lswz = ((lr >> 1) & 7) << 4;

    int koff[4];
    #pragma unroll
    for (int ks = 0; ks < 4; ++ks) koff[ks] = (ks * 32 + lk * 16) ^ lswz;
    int baseA[4];
    #pragma unroll
    for (int rb = 0; rb < 4; ++rb) baseA[rb] = (wm * 128 + rb * 32 + lr) * 128;
    int baseB = (wn * 32 + lr) * 128;

    const char* srcA[4]; const char* srcG[2]; const char* srcO[2];
    #pragma unroll
    for (int p = 0; p < 4; ++p) {
        int gr = p * 64 + w * 8 + (l >> 3);
        srcA[p] = A + (size_t)gr * (MDIM * 2) + (((l & 7) * 16) ^ swz128(gr));
    }
    #pragma unroll
    for (int p = 0; p < 2; ++p) {
        int gr = p * 64 + w * 8 + (l >> 3);
        srcG[p] = Bg + (size_t)gr * (MDIM * 2) + (((l & 7) * 16) ^ swz128(gr));
        srcO[p] = B0 + (size_t)gr * (MDIM * 2) + (((l & 7) * 16) ^ swz128(gr));
    }

    f32x16 zz;
    #pragma unroll
    for (int i = 0; i < 16; ++i) zz[i] = 0.f;
    f32x16 ag[4], ao[4];
    #pragma unroll
    for (int rb = 0; rb < 4; ++rb) { ag[rb] = zz; ao[rb] = zz; }

    auto stage = [&](int tt) {
        int kk = tt * 128;
        char* dst = smem + (tt & 1) * 65536;
        #pragma unroll
        for (int p = 0; p < 4; ++p)
            gload16(srcA[p] + kk, dst + (p * 64 + w * 8) * 128);
        #pragma unroll
        for (int p = 0; p < 2; ++p) {
            gload16(srcG[p] + kk, dst + 32768 + (p * 64 + w * 8) * 128);
            gload16(srcO[p] + kk, dst + 49152 + (p * 64 + w * 8) * 128);
        }
    };

    stage(0);
    asm volatile("s_waitcnt vmcnt(0)" ::: "memory");
    BAR();

    #pragma unroll 1
    for (int t = 0; t < NK; ++t) {
        if (t + 1 < NK) stage(t + 1);
        const char* bufc = smem + (t & 1) * 65536;
        #pragma unroll
        for (int ks = 0; ks < 4; ++ks) {
            bf16x8 bg = *(const bf16x8*)(bufc + 32768 + baseB + koff[ks]);
            bf16x8 bo = *(const bf16x8*)(bufc + 49152 + baseB + koff[ks]);
            bf16x8 af[4];
            #pragma unroll
            for (int rb = 0; rb < 4; ++rb)
                af[rb] = *(const bf16x8*)(bufc + baseA[rb] + koff[ks]);
            __builtin_amdgcn_s_setprio(1);
            #pragma unroll
            for (int rb = 0; rb < 4; ++rb) {
                ag[rb] = MFMA32(bg, af[rb], ag[rb]);
                ao[rb] = MFMA32(bo, af[rb], ao[rb]);
            }
            __builtin_amdgcn_s_setprio(0);
        }
        asm volatile("s_waitcnt vmcnt(0)" ::: "memory");
        BAR();
    }

    u16* He = Hb + (size_t)e * GC * HDIM;
    int row0 = mt * 256 + wm * 128 + lr;
    int col0 = nt * 128 + wn * 32 + lk * 4;
    #pragma unroll
    for (int rb = 0; rb < 4; ++rb) {
        size_t rowoff = (size_t)(row0 + rb * 32) * HDIM;
        #pragma unroll
        for (int q = 0; q < 4; ++q) {
            s16x4 pk;
            #pragma unroll
            for (int r = 0; r < 4; ++r) {
                float gv = ag[rb][q * 4 + r], ov = ao[rb][q * 4 + r];
                float hv = gv / (1.f + __expf(-gv)) * ov;
                pk[r] = (short)f2bf(hv);
            }
            *(s16x4*)(He + rowoff + col0 + q * 8) = pk;
        }
    }
}

// ======================================================================
// GEMM3 (R9-proven v9): 32x32x16, BM=128 BN=256 BK=64, ring-2 LDS 96KiB.
// ======================================================================
__global__ __launch_bounds__(512, 1) void gemm_out_v9(
        const u16* __restrict__ Hb, const u16* __restrict__ WoT,
        float* __restrict__ EO) {
    extern __shared__ char smem[];
    const int NK = HDIM / 64;                      // 64
    int bid = blockIdx.x;
    int swz = (bid & 7) * 80 + (bid >> 3);         // bijective (640 % 8 == 0)
    int nt = swz & 3, mt = (swz / 4) % 20, e = swz / 80;
    const char* A = (const char*)(Hb  + (size_t)e * GC * HDIM   + (size_t)mt * 128 * HDIM);
    const char* B = (const char*)(WoT + (size_t)e * MDIM * HDIM + (size_t)nt * 256 * HDIM);
    int tid = threadIdx.x, w = tid >> 6, l = tid & 63;
    int wm = w >> 2, wn = w & 3;
    int lr = l & 31, lk = l >> 5;
    int lswz = ((lr >> 1) & 7) << 4;

    int koff[4];
    #pragma unroll
    for (int ks = 0; ks < 4; ++ks) koff[ks] = (ks * 32 + lk * 16) ^ lswz;
    int baseA[2], baseB[2];
    #pragma unroll
    for (int rb = 0; rb < 2; ++rb) baseA[rb] = (wm * 64 + rb * 32 + lr) * 128;
    #pragma unroll
    for (int cb = 0; cb < 2; ++cb) baseB[cb] = (wn * 64 + cb * 32 + lr) * 128;

    const char* srcA[2]; const char* srcB[4];
    #pragma unroll
    for (int p = 0; p < 2; ++p) {
        int gr = p * 64 + w * 8 + (l >> 3);
        srcA[p] = A + (size_t)gr * (HDIM * 2) + (((l & 7) * 16) ^ swz128(gr));
    }
    #pragma unroll
    for (int p = 0; p < 4; ++p) {
        int gr = p * 64 + w * 8 + (l >> 3);
        srcB[p] = B + (size_t)gr * (HDIM * 2) + (((l & 7) * 16) ^ swz128(gr));
    }

    f32x16 zz;
    #pragma unroll
    for (int i = 0; i < 16; ++i) zz[i] = 0.f;
    f32x16 acc[2][2];
    #pragma unroll
    for (int i = 0; i < 2; ++i)
        #pragma unroll
        for (int j = 0; j < 2; ++j) acc[i][j] = zz;

    auto stage = [&](int tt) {
        int kk = tt * 128;
        char* dst = smem + (tt & 1) * 49152;
        #pragma unroll
        for (int p = 0; p < 2; ++p)
            gload16(srcA[p] + kk, dst + (p * 64 + w * 8) * 128);
        #pragma unroll
        for (int p = 0; p < 4; ++p)
            gload16(srcB[p] + kk, dst + 16384 + (p * 64 + w * 8) * 128);
    };

    stage(0);
    asm volatile("s_waitcnt vmcnt(0)" ::: "memory");
    BAR();

    #pragma unroll 1
    for (int t = 0; t < NK; ++t) {
        if (t + 1 < NK) stage(t + 1);
        const char* bufc = smem + (t & 1) * 49152;
        #pragma unroll
        for (int ks = 0; ks < 4; ++ks) {
            bf16x8 bf[2], af[2];
            #pragma unroll
            for (int cb = 0; cb < 2; ++cb)
                bf[cb] = *(const bf16x8*)(bufc + 16384 + baseB[cb] + koff[ks]);
            #pragma unroll
            for (int rb = 0; rb < 2; ++rb)
                af[rb] = *(const bf16x8*)(bufc + baseA[rb] + koff[ks]);
            __builtin_amdgcn_s_setprio(1);
            #pragma unroll
            for (int rb = 0; rb < 2; ++rb)
                #pragma unroll
                for (int cb = 0; cb < 2; ++cb)
                    acc[rb][cb] = MFMA32(bf[cb], af[rb], acc[rb][cb]);
            __builtin_amdgcn_s_setprio(0);
        }
        asm volatile("s_waitcnt vmcnt(0)" ::: "memory");
        BAR();
    }

    float* Ee = EO + (size_t)e * GC * MDIM;
    int row0 = mt * 128 + wm * 64 + lr;
    int col0 = nt * 256 + wn * 64 + lk * 4;
    #pragma unroll
    for (int rb = 0; rb < 2; ++rb) {
        size_t rowoff = (size_t)(row0 + rb * 32) * MDIM;
        #pragma unroll
        for (int cb = 0; cb < 2; ++cb)
            #pragma unroll
            for (int q = 0; q < 4; ++q) {
                f32x4 v;
                #pragma unroll
                for (int r = 0; r < 4; ++r) v[r] = acc[rb][cb][q * 4 + r];
                *(f32x4*)(Ee + rowoff + col0 + cb * 32 + q * 8) = v;
            }
    }
}

// ============ combine (blocks 0..8191) + aux_final (block 8192) ============
__global__ __launch_bounds__(256) void combine_aux_kernel(
        const float* __restrict__ EO, const int* __restrict__ top_i,
        const float* __restrict__ top_p, const int* __restrict__ token_c,
        const float* __restrict__ sums, float* __restrict__ out) {
    int bid = blockIdx.x;
    if (bid == G * S) {
        if (threadIdx.x == 0) {
            float lb = 0.f, z = 0.f;
            for (int g = 0; g < G; ++g) {
                for (int e = 0; e < E; ++e)
                    lb += (sums[g*17 + 8 + e] / (float)S) * (sums[g*17 + e] / (float)S);
                z += sums[g*17 + 16];
            }
            lb = lb / (float)(G * E) * (float)(E * E);
            z /= (float)(G * S);
            out[(size_t)G * S * MDIM] = 0.01f * lb + 0.001f * z;
        }
        return;
    }
    int tok = bid, t = threadIdx.x;
    int g = tok >> 11;
    f32x4 acc = {0.f, 0.f, 0.f, 0.f};
    #pragma unroll
    for (int k = 0; k < 2; ++k) {
        int c = token_c[tok * 2 + k];
        if (c >= 0) {
            int e = top_i[tok * 2 + k];
            float p = top_p[tok * 2 + k];
            const float* src = EO + ((size_t)e * GC + g * CAP + c) * MDIM + t * 4;
            f32x4 v = *(const f32x4*)src;
            #pragma unroll
            for (int j = 0; j < 4; ++j) acc[j] += p * v[j];
        }
    }
    *(f32x4*)(out + (size_t)tok * MDIM + t * 4) = acc;
}

extern "C" void kernel_launch(void* const* d_in, const int* in_sizes, int n_in,
                              void* d_out, int out_size, void* d_ws, size_t ws_size,
                              hipStream_t stream) {
    (void)in_sizes; (void)n_in; (void)out_size; (void)ws_size;
    const float* inputs   = (const float*)d_in[0];
    const float* paddings = (const float*)d_in[1];
    const float* router_w = (const float*)d_in[2];
    const float* wi_gate  = (const float*)d_in[3];
    const float* wi_0     = (const float*)d_in[4];
    const float* wo       = (const float*)d_in[5];
    float* out = (float*)d_out;

    char* p = (char*)d_ws;
    u16* WgT = (u16*)p; p += (size_t)E * HDIM * MDIM * 2;
    u16* W0T = (u16*)p; p += (size_t)E * HDIM * MDIM * 2;
    u16* WoT = (u16*)p; p += (size_t)E * HDIM * MDIM * 2;
    u16* Xb  = (u16*)p; p += (size_t)E * GC * MDIM * 2;
    u16* Hb  = (u16*)p; p += (size_t)E * GC * HDIM * 2;
    float* EO = (float*)p; p += (size_t)E * GC * MDIM * 4;
    int*   top_i = (int*)p;   p += (size_t)G * S * TOPK * 4;
    float* top_p = (float*)p; p += (size_t)G * S * TOPK * 4;
    int*   token_c = (int*)p; p += (size_t)G * S * TOPK * 4;
    int*   slot_token = (int*)p; p += (size_t)E * G * CAP * 4;
    float* partials = (float*)p; p += (size_t)RBLK * 17 * 4;
    float* sums = (float*)p; p += 4 * 17 * 4;

    hipMemsetAsync(token_c, 0xFF, (size_t)G * S * TOPK * 4, stream);
    hipMemsetAsync(slot_token, 0xFF, (size_t)E * G * CAP * 4, stream);

    hipFuncSetAttribute((const void*)gemm_ffn12_v9,
                        hipFuncAttributeMaxDynamicSharedMemorySize, 131072);
    hipFuncSetAttribute((const void*)gemm_out_v9,
                        hipFuncAttributeMaxDynamicSharedMemorySize, 98304);

    // router (2048) + wi_gate T (8192) + wi_0 T (8192) + wo T (8192)
    prep_kernel<<<RBLK + 24576, 256, 0, stream>>>(inputs, router_w, wi_gate, wi_0, wo,
                                                  WgT, W0T, WoT, top_i, top_p, partials);
    // scan (32) + reduce_partials (4)
    scan_reduce_kernel<<<36, 256, 0, stream>>>(top_i, paddings, partials,
                                               slot_token, token_c, sums);
    gather_kernel<<<E * GC, 128, 0, stream>>>(inputs, slot_token, Xb);
    gemm_ffn12_v9<<<2560, 512, 131072, stream>>>(Xb, WgT, W0T, Hb);
    gemm_out_v9<<<640, 512, 98304, stream>>>(Hb, WoT, EO);
    // combine (8192) + aux_final (1)
    combine_aux_kernel<<<G * S + 1, 256, 0, stream>>>(EO, top_i, top_p, token_c,
                                                      sums, out);
}

// Round 13
// 762.621 us; speedup vs baseline: 1.3865x; 1.0008x over previous
//
#include <hip/hip_runtime.h>
#include <hip/hip_bf16.h>
#include <math.h>

#define G 4
#define S 2048
#define MDIM 1024
#define E 8
#define HDIM 4096
#define TOPK 2
#define CAP 640
#define GC (G*CAP)      /* 2560 rows per expert */
#define RBLK (G*S/4)    /* 2048 router blocks, 4 tokens each */

typedef __attribute__((ext_vector_type(8))) short bf16x8;
typedef __attribute__((ext_vector_type(4))) short s16x4;
typedef __attribute__((ext_vector_type(4))) float f32x4;
typedef __attribute__((ext_vector_type(16))) float f32x16;
typedef unsigned int u32;
typedef unsigned short u16;

#define MFMA16(a,b,c) __builtin_amdgcn_mfma_f32_16x16x32_bf16(a,b,c,0,0,0)
#define MFMA32(a,b,c) __builtin_amdgcn_mfma_f32_32x32x16_bf16(a,b,c,0,0,0)
#define BAR() __builtin_amdgcn_s_barrier()
#define SB0() __builtin_amdgcn_sched_barrier(0)
#define LGKM0() asm volatile("s_waitcnt lgkmcnt(0)" ::: "memory")

__device__ __forceinline__ u16 f2bf(float f) {
    union { float f; u32 u; } v; v.f = f;
    u32 r = v.u + 0x7fffu + ((v.u >> 16) & 1u);
    return (u16)(r >> 16);
}

__device__ __forceinline__ void gload16(const char* gp, char* lp) {
    __builtin_amdgcn_global_load_lds((const __attribute__((address_space(1))) u32*)gp,
                                     (__attribute__((address_space(3))) u32*)lp,
                                     16, 0, 0);
}

// XOR swizzles (involution; applied to global SOURCE + LDS READ, rule 21)
__device__ __forceinline__ int swz128(int r) { return ((r >> 1) & 7) << 4; }  // 128B rows
__device__ __forceinline__ int swz64(int r)  { return ((r >> 1) & 3) << 4; }  // 64B rows

// ============ fused prep: router (blocks 0..2047) + 3 transposes ============
__device__ void transpose_body(const float* __restrict__ in, u16* __restrict__ out,
                               int R, int C, int tb, float (*tile)[68]) {
    int nbx = C / 64, nby = R / 64;
    int bx = tb % nbx, by = (tb / nbx) % nby, e = tb / (nbx * nby);
    const float* ine = in + (size_t)e * R * C;
    u16* oute = out + (size_t)e * R * C;
    int t = threadIdx.x;
    int x0 = bx * 64, y0 = by * 64;
    int lx = (t & 15) * 4, ly = t >> 4;
    #pragma unroll
    for (int i = 0; i < 4; ++i) {
        f32x4 v = *(const f32x4*)(ine + (size_t)(y0 + ly + i * 16) * C + x0 + lx);
        *(f32x4*)&tile[ly + i * 16][lx] = v;
    }
    __syncthreads();
    int rr0 = (t & 15) * 4, cb = t >> 4;
    #pragma unroll
    for (int p = 0; p < 4; ++p) {
        int cc = cb + p * 16;
        s16x4 pk;
        #pragma unroll
        for (int j = 0; j < 4; ++j) pk[j] = (short)f2bf(tile[rr0 + j][cc]);
        *(s16x4*)(oute + (size_t)(x0 + cc) * R + y0 + rr0) = pk;
    }
}

__global__ __launch_bounds__(256) void prep_kernel(
        const float* __restrict__ inp, const float* __restrict__ rw,
        const float* __restrict__ wi_gate, const float* __restrict__ wi_0,
        const float* __restrict__ wo,
        u16* __restrict__ WgT, u16* __restrict__ W0T, u16* __restrict__ WoT,
        int* __restrict__ top_i, float* __restrict__ top_p,
        float* __restrict__ partials) {
    __shared__ float tile[64][68];
    __shared__ float part[4][17];
    int bid = blockIdx.x;
    if (bid >= RBLK) {
        int tb = bid - RBLK;
        if (tb < 8192)       transpose_body(wi_gate, WgT, MDIM, HDIM, tb, tile);
        else if (tb < 16384) transpose_body(wi_0,   W0T, MDIM, HDIM, tb - 8192, tile);
        else                 transpose_body(wo,     WoT, HDIM, MDIM, tb - 16384, tile);
        return;
    }
    int wid = threadIdx.x >> 6, lane = threadIdx.x & 63;
    int tok = bid * 4 + wid;
    const float* x = inp + (size_t)tok * MDIM;
    float acc[E] = {0.f,0.f,0.f,0.f,0.f,0.f,0.f,0.f};
    #pragma unroll
    for (int rep = 0; rep < 4; ++rep) {
        int m0 = rep * 256 + lane * 4;
        f32x4 xv = *(const f32x4*)(x + m0);
        #pragma unroll
        for (int j = 0; j < 4; ++j) {
            const float* r = rw + (size_t)(m0 + j) * E;
            float xj = xv[j];
            #pragma unroll
            for (int e = 0; e < E; ++e) acc[e] += xj * r[e];
        }
    }
    #pragma unroll
    for (int e = 0; e < E; ++e)
        #pragma unroll
        for (int off = 32; off; off >>= 1) acc[e] += __shfl_down(acc[e], off);

    if (lane == 0) {
        float mx = acc[0];
        #pragma unroll
        for (int e = 1; e < E; ++e) mx = fmaxf(mx, acc[e]);
        float p[E], sum = 0.f;
        #pragma unroll
        for (int e = 0; e < E; ++e) { p[e] = expf(acc[e] - mx); sum += p[e]; }
        float inv = 1.f / sum;
        #pragma unroll
        for (int e = 0; e < E; ++e) p[e] *= inv;
        float lse = logf(sum) + mx;
        int i0 = 0;
        #pragma unroll
        for (int e = 1; e < E; ++e) if (acc[e] > acc[i0]) i0 = e;
        int i1 = (i0 == 0) ? 1 : 0;
        #pragma unroll
        for (int e = 0; e < E; ++e) if (e != i0 && acc[e] > acc[i1]) i1 = e;
        top_i[tok*2+0] = i0; top_i[tok*2+1] = i1;
        top_p[tok*2+0] = p[i0]; top_p[tok*2+1] = p[i1];
        #pragma unroll
        for (int e = 0; e < E; ++e) { part[wid][e] = p[e]; part[wid][8+e] = 0.f; }
        part[wid][8+i0] = 1.f; part[wid][8+i1] = 1.f;
        part[wid][16] = lse * lse;
    }
    __syncthreads();
    if (threadIdx.x < 17) {
        float v = part[0][threadIdx.x] + part[1][threadIdx.x] +
                  part[2][threadIdx.x] + part[3][threadIdx.x];
        partials[(size_t)bid * 17 + threadIdx.x] = v;
    }
}

// ============ fused scan (blocks 0..31) + reduce_partials (32..35) ============
__global__ __launch_bounds__(256) void scan_reduce_kernel(
        const int* __restrict__ top_i, const float* __restrict__ pad,
        const float* __restrict__ partials,
        int* __restrict__ slot_token, int* __restrict__ token_c,
        float* __restrict__ sums_out) {
    __shared__ int sums[256];
    __shared__ float red[256];
    int bid = blockIdx.x;
    int t = threadIdx.x;
    if (bid >= 32) {
        int g = bid - 32;
        float loc[17];
        #pragma unroll
        for (int c = 0; c < 17; ++c) loc[c] = 0.f;
        for (int r = t; r < 512; r += 256) {
            const float* pr = partials + ((size_t)g * 512 + r) * 17;
            #pragma unroll
            for (int c = 0; c < 17; ++c) loc[c] += pr[c];
        }
        for (int c = 0; c < 17; ++c) {
            red[t] = loc[c]; __syncthreads();
            for (int off = 128; off; off >>= 1) {
                if (t < off) red[t] += red[t + off];
                __syncthreads();
            }
            if (t == 0) sums_out[g * 17 + c] = red[0];
            __syncthreads();
        }
        return;
    }
    int g = bid >> 3, e = bid & 7;
    int base = t * 16;
    int run = 0; unsigned mask16 = 0; int loc[16];
    #pragma unroll
    for (int j = 0; j < 16; ++j) {
        int i = base + j; int s = i >> 1, k = i & 1;
        int ex = top_i[((size_t)(g * S + s)) * 2 + k];
        int m = (ex == e) && (pad[g * S + s] == 0.f);
        run += m; loc[j] = run; mask16 |= ((unsigned)m << j);
    }
    sums[t] = run; __syncthreads();
    for (int off = 1; off < 256; off <<= 1) {
        int v = (t >= off) ? sums[t - off] : 0;
        __syncthreads();
        sums[t] += v;
        __syncthreads();
    }
    int excl = sums[t] - run;
    #pragma unroll
    for (int j = 0; j < 16; ++j) {
        if ((mask16 >> j) & 1u) {
            int pos = excl + loc[j];
            if (pos <= CAP) {
                int i = base + j; int s = i >> 1, k = i & 1;
                slot_token[((size_t)(e * G + g)) * CAP + (pos - 1)] = s;
                token_c[((size_t)(g * S + s)) * 2 + k] = pos - 1;
            }
        }
    }
}

// ---------------- gather tokens -> X bf16 [E][GC][MDIM] ----------------
__global__ __launch_bounds__(128) void gather_kernel(const float* __restrict__ inp,
                                                     const int* __restrict__ slot_token,
                                                     u16* __restrict__ X) {
    int row = blockIdx.x;
    int t = threadIdx.x;
    int s = slot_token[row];
    int g = (row % GC) / CAP;
    bf16x8 v;
    if (s >= 0) {
        const float* src = inp + ((size_t)(g * S + s)) * MDIM + t * 8;
        f32x4 a = *(const f32x4*)src;
        f32x4 b = *(const f32x4*)(src + 4);
        #pragma unroll
        for (int j = 0; j < 4; ++j) { v[j] = (short)f2bf(a[j]); v[4+j] = (short)f2bf(b[j]); }
    } else {
        #pragma unroll
        for (int j = 0; j < 8; ++j) v[j] = 0;
    }
    *(bf16x8*)(X + (size_t)row * MDIM + t * 8) = v;
}

// ======================================================================
// GEMM1+2 fused v11: m201-template port, dual-B. 16x16x32 MFMA.
// BM=256 BN=128 BK=64 (2 K-halves of 32), 8 waves 2Mx4N, wave 128x32x2B.
// LDS ring-2 x {A_k0 16K, A_k1 16K, Bg_k0 8K, B0_k0 8K, Bg_k1 8K, B0_k1 8K}
//   = 2 x 64K = 128 KiB.
// 4 phases/K-step: {<=8 ds_reads; stage 2-load unit; SB; [vmcnt]; BAR;
//   lgkm0; SB; prio1; 16 MFMA; prio0; BAR}. Stage runs 1.5 K-steps ahead;
// vmcnt(8) at phases 2,4 (never 0 steady-state).
// ======================================================================
__global__ __launch_bounds__(512, 1) void gemm_ffn12_v11(
        const u16* __restrict__ Xb, const u16* __restrict__ WgT,
        const u16* __restrict__ W0T, u16* __restrict__ Hb) {
    extern __shared__ char smem[];
    const int NK = MDIM / 64;                      // 16
    int bid = blockIdx.x;
    int swz = (bid & 7) * 320 + (bid >> 3);        // bijective (2560 % 8 == 0)
    int mt = swz % 10, nt = (swz / 10) & 31, e = swz / 320;
    const char* A  = (const char*)(Xb  + (size_t)e * GC * MDIM   + (size_t)mt * 256 * MDIM);
    const char* Bg = (const char*)(WgT + (size_t)e * HDIM * MDIM + (size_t)nt * 128 * MDIM);
    const char* B0 = (const char*)(W0T + (size_t)e * HDIM * MDIM + (size_t)nt * 128 * MDIM);
    int tid = threadIdx.x, w = tid >> 6, l = tid & 63;
    int wm = w >> 2, wn = w & 3;                   // 2M x 4N waves
    int fr = l & 15, fg = l >> 4;                  // frag row, k-group

    // ---- staging sources (per-lane, swizzled; wave-uniform LDS dests) ----
    // A unit (16KB): wave w, load i covers LDS rows (w*2+i)*16 + (l>>2)
    int grA0 = (w * 2 + 0) * 16 + (l >> 2), grA1 = (w * 2 + 1) * 16 + (l >> 2);
    const char* srcA0 = A + (size_t)grA0 * (MDIM * 2) + (((l & 3) * 16) ^ swz64(grA0));
    const char* srcA1 = A + (size_t)grA1 * (MDIM * 2) + (((l & 3) * 16) ^ swz64(grA1));
    // B units (8KB each): wave w covers rows w*16 + (l>>2)
    int grB = w * 16 + (l >> 2);
    const char* srcG = Bg + (size_t)grB * (MDIM * 2) + (((l & 3) * 16) ^ swz64(grB));
    const char* srcO = B0 + (size_t)grB * (MDIM * 2) + (((l & 3) * 16) ^ swz64(grB));

    // ---- LDS read base offsets (per-lane, swizzled) ----
    int baseAr[8];
    #pragma unroll
    for (int fm = 0; fm < 8; ++fm) {
        int r = wm * 128 + fm * 16 + fr;
        baseAr[fm] = r * 64 + ((fg * 16) ^ swz64(r));
    }
    int baseGr[2], baseOr[2];
    #pragma unroll
    for (int fn = 0; fn < 2; ++fn) {
        int r = wn * 32 + fn * 16 + fr;
        baseGr[fn] = 32768 + r * 64 + ((fg * 16) ^ swz64(r));
        baseOr[fn] = baseGr[fn] + 8192;
    }

    f32x4 ag[8][2], ao[8][2];
    #pragma unroll
    for (int i = 0; i < 8; ++i) {
        ag[i][0] = (f32x4){0,0,0,0}; ag[i][1] = (f32x4){0,0,0,0};
        ao[i][0] = (f32x4){0,0,0,0}; ao[i][1] = (f32x4){0,0,0,0};
    }

    auto stageA = [&](int tt, int ks) {            // 2 loads
        int kk = tt * 128 + ks * 64;
        char* dst = smem + (tt & 1) * 65536 + ks * 16384;
        gload16(srcA0 + kk, dst + (w * 2 + 0) * 1024);
        gload16(srcA1 + kk, dst + (w * 2 + 1) * 1024);
    };
    auto stageBB = [&](int tt, int ks) {           // 2 loads (Bg + B0)
        int kk = tt * 128 + ks * 64;
        char* dst = smem + (tt & 1) * 65536 + 32768 + ks * 16384 + w * 1024;
        gload16(srcG + kk, dst);
        gload16(srcO + kk, dst + 8192);
    };

    // prologue: t0 fully + t1 first units; retire t0; leave A0(1),BB0(1) in flight
    stageA(0, 0); stageBB(0, 0); stageA(0, 1); stageBB(0, 1);
    stageA(1, 0); stageBB(1, 0);
    asm volatile("s_waitcnt vmcnt(4)" ::: "memory");
    BAR();

    bf16x8 bgf[2], bof[2];

    #pragma unroll 1
    for (int t = 0; t < NK; ++t) {
        const char* buf = smem + (t & 1) * 65536;
        #pragma unroll
        for (int ks = 0; ks < 2; ++ks) {
            const char* bks = buf + ks * 16384;
            // ---- phase (ks, lo): fm 0-3, fresh B frags ----
            bf16x8 af[4];
            bgf[0] = *(const bf16x8*)(bks + baseGr[0]);
            bgf[1] = *(const bf16x8*)(bks + baseGr[1]);
            bof[0] = *(const bf16x8*)(bks + baseOr[0]);
            bof[1] = *(const bf16x8*)(bks + baseOr[1]);
            #pragma unroll
            for (int j = 0; j < 4; ++j) af[j] = *(const bf16x8*)(bks + baseAr[j]);
            if (ks == 0) { if (t + 1 < NK) stageA(t + 1, 1); }
            else         { if (t + 2 < NK) stageA(t + 2, 0); }
            SB0();
            BAR();
            LGKM0(); SB0();
            __builtin_amdgcn_s_setprio(1);
            #pragma unroll
            for (int fm = 0; fm < 4; ++fm)
                #pragma unroll
                for (int fn = 0; fn < 2; ++fn) {
                    ag[fm][fn] = MFMA16(bgf[fn], af[fm], ag[fm][fn]);
                    ao[fm][fn] = MFMA16(bof[fn], af[fm], ao[fm][fn]);
                }
            __builtin_amdgcn_s_setprio(0);
            BAR();
            // ---- phase (ks, hi): fm 4-7, reuse B frags ----
            bf16x8 ah[4];
            #pragma unroll
            for (int j = 0; j < 4; ++j) ah[j] = *(const bf16x8*)(bks + baseAr[4 + j]);
            if (ks == 0) { if (t + 1 < NK) stageBB(t + 1, 1); }
            else         { if (t + 2 < NK) stageBB(t + 2, 0); }
            SB0();
            if (ks == 0) {
                // need A_k1(t), BB_k1(t) complete; newer = up to 4 units
                if (t + 1 < NK) { asm volatile("s_waitcnt vmcnt(8)" ::: "memory"); }
                else            { asm volatile("s_waitcnt vmcnt(0)" ::: "memory"); }
            } else {
                // need A_k0(t+1), BB_k0(t+1) complete; newer = up to 4 units
                if (t + 2 < NK)      { asm volatile("s_waitcnt vmcnt(8)" ::: "memory"); }
                else if (t + 1 < NK) { asm volatile("s_waitcnt vmcnt(4)" ::: "memory"); }
                else                 { asm volatile("s_waitcnt vmcnt(0)" ::: "memory"); }
            }
            BAR();
            LGKM0(); SB0();
            __builtin_amdgcn_s_setprio(1);
            #pragma unroll
            for (int fm = 0; fm < 4; ++fm)
                #pragma unroll
                for (int fn = 0; fn < 2; ++fn) {
                    ag[4+fm][fn] = MFMA16(bgf[fn], ah[fm], ag[4+fm][fn]);
                    ao[4+fm][fn] = MFMA16(bof[fn], ah[fm], ao[4+fm][fn]);
                }
            __builtin_amdgcn_s_setprio(0);
            BAR();
        }
    }

    // epilogue: silu(g)*o, packed 8B bf16 stores (v4-proven layout)
    u16* He = Hb + (size_t)e * GC * HDIM;
    int row0 = mt * 256 + wm * 128 + fr;
    int col0 = nt * 128 + wn * 32 + fg * 4;
    #pragma unroll
    for (int fm = 0; fm < 8; ++fm)
        #pragma unroll
        for (int fn = 0; fn < 2; ++fn) {
            s16x4 pk;
            #pragma unroll
            for (int r = 0; r < 4; ++r) {
                float gv = ag[fm][fn][r], ov = ao[fm][fn][r];
                float hv = gv / (1.f + __expf(-gv)) * ov;
                pk[r] = (short)f2bf(hv);
            }
            *(s16x4*)(He + (size_t)(row0 + fm * 16) * HDIM + col0 + fn * 16) = pk;
        }
}

// ======================================================================
// GEMM3 (R9-proven v9): 32x32x16, BM=128 BN=256 BK=64, ring-2 LDS 96KiB.
// ======================================================================
__global__ __launch_bounds__(512, 1) void gemm_out_v9(
        const u16* __restrict__ Hb, const u16* __restrict__ WoT,
        float* __restrict__ EO) {
    extern __shared__ char smem[];
    const int NK = HDIM / 64;                      // 64
    int bid = blockIdx.x;
    int swz = (bid & 7) * 80 + (bid >> 3);         // bijective (640 % 8 == 0)
    int nt = swz & 3, mt = (swz / 4) % 20, e = swz / 80;
    const char* A = (const char*)(Hb  + (size_t)e * GC * HDIM   + (size_t)mt * 128 * HDIM);
    const char* B = (const char*)(WoT + (size_t)e * MDIM * HDIM + (size_t)nt * 256 * HDIM);
    int tid = threadIdx.x, w = tid >> 6, l = tid & 63;
    int wm = w >> 2, wn = w & 3;
    int lr = l & 31, lk = l >> 5;
    int lswz = ((lr >> 1) & 7) << 4;

    int koff[4];
    #pragma unroll
    for (int ks = 0; ks < 4; ++ks) koff[ks] = (ks * 32 + lk * 16) ^ lswz;
    int baseA[2], baseB[2];
    #pragma unroll
    for (int rb = 0; rb < 2; ++rb) baseA[rb] = (wm * 64 + rb * 32 + lr) * 128;
    #pragma unroll
    for (int cb = 0; cb < 2; ++cb) baseB[cb] = (wn * 64 + cb * 32 + lr) * 128;

    const char* srcA[2]; const char* srcB[4];
    #pragma unroll
    for (int p = 0; p < 2; ++p) {
        int gr = p * 64 + w * 8 + (l >> 3);
        srcA[p] = A + (size_t)gr * (HDIM * 2) + (((l & 7) * 16) ^ swz128(gr));
    }
    #pragma unroll
    for (int p = 0; p < 4; ++p) {
        int gr = p * 64 + w * 8 + (l >> 3);
        srcB[p] = B + (size_t)gr * (HDIM * 2) + (((l & 7) * 16) ^ swz128(gr));
    }

    f32x16 zz;
    #pragma unroll
    for (int i = 0; i < 16; ++i) zz[i] = 0.f;
    f32x16 acc[2][2];
    #pragma unroll
    for (int i = 0; i < 2; ++i)
        #pragma unroll
        for (int j = 0; j < 2; ++j) acc[i][j] = zz;

    auto stage = [&](int tt) {
        int kk = tt * 128;
        char* dst = smem + (tt & 1) * 49152;
        #pragma unroll
        for (int p = 0; p < 2; ++p)
            gload16(srcA[p] + kk, dst + (p * 64 + w * 8) * 128);
        #pragma unroll
        for (int p = 0; p < 4; ++p)
            gload16(srcB[p] + kk, dst + 16384 + (p * 64 + w * 8) * 128);
    };

    stage(0);
    asm volatile("s_waitcnt vmcnt(0)" ::: "memory");
    BAR();

    #pragma unroll 1
    for (int t = 0; t < NK; ++t) {
        if (t + 1 < NK) stage(t + 1);
        const char* bufc = smem + (t & 1) * 49152;
        #pragma unroll
        for (int ks = 0; ks < 4; ++ks) {
            bf16x8 bf[2], af[2];
            #pragma unroll
            for (int cb = 0; cb < 2; ++cb)
                bf[cb] = *(const bf16x8*)(bufc + 16384 + baseB[cb] + koff[ks]);
            #pragma unroll
            for (int rb = 0; rb < 2; ++rb)
                af[rb] = *(const bf16x8*)(bufc + baseA[rb] + koff[ks]);
            __builtin_amdgcn_s_setprio(1);
            #pragma unroll
            for (int rb = 0; rb < 2; ++rb)
                #pragma unroll
                for (int cb = 0; cb < 2; ++cb)
                    acc[rb][cb] = MFMA32(bf[cb], af[rb], acc[rb][cb]);
            __builtin_amdgcn_s_setprio(0);
        }
        asm volatile("s_waitcnt vmcnt(0)" ::: "memory");
        BAR();
    }

    float* Ee = EO + (size_t)e * GC * MDIM;
    int row0 = mt * 128 + wm * 64 + lr;
    int col0 = nt * 256 + wn * 64 + lk * 4;
    #pragma unroll
    for (int rb = 0; rb < 2; ++rb) {
        size_t rowoff = (size_t)(row0 + rb * 32) * MDIM;
        #pragma unroll
        for (int cb = 0; cb < 2; ++cb)
            #pragma unroll
            for (int q = 0; q < 4; ++q) {
                f32x4 v;
                #pragma unroll
                for (int r = 0; r < 4; ++r) v[r] = acc[rb][cb][q * 4 + r];
                *(f32x4*)(Ee + rowoff + col0 + cb * 32 + q * 8) = v;
            }
    }
}

// ============ combine (blocks 0..8191) + aux_final (block 8192) ============
__global__ __launch_bounds__(256) void combine_aux_kernel(
        const float* __restrict__ EO, const int* __restrict__ top_i,
        const float* __restrict__ top_p, const int* __restrict__ token_c,
        const float* __restrict__ sums, float* __restrict__ out) {
    int bid = blockIdx.x;
    if (bid == G * S) {
        if (threadIdx.x == 0) {
            float lb = 0.f, z = 0.f;
            for (int g = 0; g < G; ++g) {
                for (int e = 0; e < E; ++e)
                    lb += (sums[g*17 + 8 + e] / (float)S) * (sums[g*17 + e] / (float)S);
                z += sums[g*17 + 16];
            }
            lb = lb / (float)(G * E) * (float)(E * E);
            z /= (float)(G * S);
            out[(size_t)G * S * MDIM] = 0.01f * lb + 0.001f * z;
        }
        return;
    }
    int tok = bid, t = threadIdx.x;
    int g = tok >> 11;
    f32x4 acc = {0.f, 0.f, 0.f, 0.f};
    #pragma unroll
    for (int k = 0; k < 2; ++k) {
        int c = token_c[tok * 2 + k];
        if (c >= 0) {
            int e = top_i[tok * 2 + k];
            float p = top_p[tok * 2 + k];
            const float* src = EO + ((size_t)e * GC + g * CAP + c) * MDIM + t * 4;
            f32x4 v = *(const f32x4*)src;
            #pragma unroll
            for (int j = 0; j < 4; ++j) acc[j] += p * v[j];
        }
    }
    *(f32x4*)(out + (size_t)tok * MDIM + t * 4) = acc;
}

extern "C" void kernel_launch(void* const* d_in, const int* in_sizes, int n_in,
                              void* d_out, int out_size, void* d_ws, size_t ws_size,
                              hipStream_t stream) {
    (void)in_sizes; (void)n_in; (void)out_size; (void)ws_size;
    const float* inputs   = (const float*)d_in[0];
    const float* paddings = (const float*)d_in[1];
    const float* router_w = (const float*)d_in[2];
    const float* wi_gate  = (const float*)d_in[3];
    const float* wi_0     = (const float*)d_in[4];
    const float* wo       = (const float*)d_in[5];
    float* out = (float*)d_out;

    char* p = (char*)d_ws;
    u16* WgT = (u16*)p; p += (size_t)E * HDIM * MDIM * 2;
    u16* W0T = (u16*)p; p += (size_t)E * HDIM * MDIM * 2;
    u16* WoT = (u16*)p; p += (size_t)E * HDIM * MDIM * 2;
    u16* Xb  = (u16*)p; p += (size_t)E * GC * MDIM * 2;
    u16* Hb  = (u16*)p; p += (size_t)E * GC * HDIM * 2;
    float* EO = (float*)p; p += (size_t)E * GC * MDIM * 4;
    int*   top_i = (int*)p;   p += (size_t)G * S * TOPK * 4;
    float* top_p = (float*)p; p += (size_t)G * S * TOPK * 4;
    int*   token_c = (int*)p; p += (size_t)G * S * TOPK * 4;
    int*   slot_token = (int*)p; p += (size_t)E * G * CAP * 4;
    float* partials = (float*)p; p += (size_t)RBLK * 17 * 4;
    float* sums = (float*)p; p += 4 * 17 * 4;

    hipMemsetAsync(token_c, 0xFF, (size_t)G * S * TOPK * 4, stream);
    hipMemsetAsync(slot_token, 0xFF, (size_t)E * G * CAP * 4, stream);

    hipFuncSetAttribute((const void*)gemm_ffn12_v11,
                        hipFuncAttributeMaxDynamicSharedMemorySize, 131072);
    hipFuncSetAttribute((const void*)gemm_out_v9,
                        hipFuncAttributeMaxDynamicSharedMemorySize, 98304);

    prep_kernel<<<RBLK + 24576, 256, 0, stream>>>(inputs, router_w, wi_gate, wi_0, wo,
                                                  WgT, W0T, WoT, top_i, top_p, partials);
    scan_reduce_kernel<<<36, 256, 0, stream>>>(top_i, paddings, partials,
                                               slot_token, token_c, sums);
    gather_kernel<<<E * GC, 128, 0, stream>>>(inputs, slot_token, Xb);
    gemm_ffn12_v11<<<2560, 512, 131072, stream>>>(Xb, WgT, W0T, Hb);
    gemm_out_v9<<<640, 512, 98304, stream>>>(Hb, WoT, EO);
    combine_aux_kernel<<<G * S + 1, 256, 0, stream>>>(EO, top_i, top_p, token_c,
                                                      sums, out);
}

// Round 14
// 685.004 us; speedup vs baseline: 1.5436x; 1.1133x over previous
//
#include <hip/hip_runtime.h>
#include <hip/hip_bf16.h>
#include <math.h>

#define G 4
#define S 2048
#define MDIM 1024
#define E 8
#define HDIM 4096
#define TOPK 2
#define CAP 640
#define GC (G*CAP)      /* 2560 rows per expert */
#define RBLK (G*S/4)    /* 2048 router blocks, 4 tokens each */

typedef __attribute__((ext_vector_type(8))) short bf16x8;
typedef __attribute__((ext_vector_type(4))) short s16x4;
typedef __attribute__((ext_vector_type(4))) float f32x4;
typedef __attribute__((ext_vector_type(16))) float f32x16;
typedef unsigned int u32;
typedef unsigned short u16;

#define MFMA32(a,b,c) __builtin_amdgcn_mfma_f32_32x32x16_bf16(a,b,c,0,0,0)
#define BAR() __builtin_amdgcn_s_barrier()

__device__ __forceinline__ u16 f2bf(float f) {
    union { float f; u32 u; } v; v.f = f;
    u32 r = v.u + 0x7fffu + ((v.u >> 16) & 1u);
    return (u16)(r >> 16);
}

__device__ __forceinline__ void gload16(const char* gp, char* lp) {
    __builtin_amdgcn_global_load_lds((const __attribute__((address_space(1))) u32*)gp,
                                     (__attribute__((address_space(3))) u32*)lp,
                                     16, 0, 0);
}

// 3-bit XOR swizzle for 128-byte LDS rows (involution; source+read sides)
__device__ __forceinline__ int swz128(int r) { return ((r >> 1) & 7) << 4; }

// ============ fused prep: router (blocks 0..2047) + 3 transposes ============
__device__ void transpose_body(const float* __restrict__ in, u16* __restrict__ out,
                               int R, int C, int tb, float (*tile)[68]) {
    int nbx = C / 64, nby = R / 64;
    int bx = tb % nbx, by = (tb / nbx) % nby, e = tb / (nbx * nby);
    const float* ine = in + (size_t)e * R * C;
    u16* oute = out + (size_t)e * R * C;
    int t = threadIdx.x;
    int x0 = bx * 64, y0 = by * 64;
    int lx = (t & 15) * 4, ly = t >> 4;
    #pragma unroll
    for (int i = 0; i < 4; ++i) {
        f32x4 v = *(const f32x4*)(ine + (size_t)(y0 + ly + i * 16) * C + x0 + lx);
        *(f32x4*)&tile[ly + i * 16][lx] = v;
    }
    __syncthreads();
    int rr0 = (t & 15) * 4, cb = t >> 4;
    #pragma unroll
    for (int p = 0; p < 4; ++p) {
        int cc = cb + p * 16;
        s16x4 pk;
        #pragma unroll
        for (int j = 0; j < 4; ++j) pk[j] = (short)f2bf(tile[rr0 + j][cc]);
        *(s16x4*)(oute + (size_t)(x0 + cc) * R + y0 + rr0) = pk;
    }
}

__global__ __launch_bounds__(256) void prep_kernel(
        const float* __restrict__ inp, const float* __restrict__ rw,
        const float* __restrict__ wi_gate, const float* __restrict__ wi_0,
        const float* __restrict__ wo,
        u16* __restrict__ WgT, u16* __restrict__ W0T, u16* __restrict__ WoT,
        int* __restrict__ top_i, float* __restrict__ top_p,
        float* __restrict__ partials) {
    __shared__ float tile[64][68];
    __shared__ float part[4][17];
    int bid = blockIdx.x;
    if (bid >= RBLK) {
        int tb = bid - RBLK;
        if (tb < 8192)       transpose_body(wi_gate, WgT, MDIM, HDIM, tb, tile);
        else if (tb < 16384) transpose_body(wi_0,   W0T, MDIM, HDIM, tb - 8192, tile);
        else                 transpose_body(wo,     WoT, HDIM, MDIM, tb - 16384, tile);
        return;
    }
    int wid = threadIdx.x >> 6, lane = threadIdx.x & 63;
    int tok = bid * 4 + wid;
    const float* x = inp + (size_t)tok * MDIM;
    float acc[E] = {0.f,0.f,0.f,0.f,0.f,0.f,0.f,0.f};
    #pragma unroll
    for (int rep = 0; rep < 4; ++rep) {
        int m0 = rep * 256 + lane * 4;
        f32x4 xv = *(const f32x4*)(x + m0);
        #pragma unroll
        for (int j = 0; j < 4; ++j) {
            const float* r = rw + (size_t)(m0 + j) * E;
            float xj = xv[j];
            #pragma unroll
            for (int e = 0; e < E; ++e) acc[e] += xj * r[e];
        }
    }
    #pragma unroll
    for (int e = 0; e < E; ++e)
        #pragma unroll
        for (int off = 32; off; off >>= 1) acc[e] += __shfl_down(acc[e], off);

    if (lane == 0) {
        float mx = acc[0];
        #pragma unroll
        for (int e = 1; e < E; ++e) mx = fmaxf(mx, acc[e]);
        float p[E], sum = 0.f;
        #pragma unroll
        for (int e = 0; e < E; ++e) { p[e] = expf(acc[e] - mx); sum += p[e]; }
        float inv = 1.f / sum;
        #pragma unroll
        for (int e = 0; e < E; ++e) p[e] *= inv;
        float lse = logf(sum) + mx;
        int i0 = 0;
        #pragma unroll
        for (int e = 1; e < E; ++e) if (acc[e] > acc[i0]) i0 = e;
        int i1 = (i0 == 0) ? 1 : 0;
        #pragma unroll
        for (int e = 0; e < E; ++e) if (e != i0 && acc[e] > acc[i1]) i1 = e;
        top_i[tok*2+0] = i0; top_i[tok*2+1] = i1;
        top_p[tok*2+0] = p[i0]; top_p[tok*2+1] = p[i1];
        #pragma unroll
        for (int e = 0; e < E; ++e) { part[wid][e] = p[e]; part[wid][8+e] = 0.f; }
        part[wid][8+i0] = 1.f; part[wid][8+i1] = 1.f;
        part[wid][16] = lse * lse;
    }
    __syncthreads();
    if (threadIdx.x < 17) {
        float v = part[0][threadIdx.x] + part[1][threadIdx.x] +
                  part[2][threadIdx.x] + part[3][threadIdx.x];
        partials[(size_t)bid * 17 + threadIdx.x] = v;
    }
}

// ============ fused scan (blocks 0..31) + reduce_partials (32..35) ============
// Also writes ALL -1 sentinels (dropped/padded token_c, slot_token tail) so the
// host needs no memsets. With pad==0 each (g,s,k) is written by exactly one block.
__global__ __launch_bounds__(256) void scan_reduce_kernel(
        const int* __restrict__ top_i, const float* __restrict__ pad,
        const float* __restrict__ partials,
        int* __restrict__ slot_token, int* __restrict__ token_c,
        float* __restrict__ sums_out) {
    __shared__ int sums[256];
    __shared__ float red[256];
    int bid = blockIdx.x;
    int t = threadIdx.x;
    if (bid >= 32) {
        int g = bid - 32;
        float loc[17];
        #pragma unroll
        for (int c = 0; c < 17; ++c) loc[c] = 0.f;
        for (int r = t; r < 512; r += 256) {
            const float* pr = partials + ((size_t)g * 512 + r) * 17;
            #pragma unroll
            for (int c = 0; c < 17; ++c) loc[c] += pr[c];
        }
        for (int c = 0; c < 17; ++c) {
            red[t] = loc[c]; __syncthreads();
            for (int off = 128; off; off >>= 1) {
                if (t < off) red[t] += red[t + off];
                __syncthreads();
            }
            if (t == 0) sums_out[g * 17 + c] = red[0];
            __syncthreads();
        }
        return;
    }
    int g = bid >> 3, e = bid & 7;
    int base = t * 16;
    int run = 0; unsigned mask16 = 0, emask16 = 0; int loc[16];
    #pragma unroll
    for (int j = 0; j < 16; ++j) {
        int i = base + j; int s = i >> 1, k = i & 1;
        int ex = top_i[((size_t)(g * S + s)) * 2 + k];
        int me = (ex == e);
        int m = me && (pad[g * S + s] == 0.f);
        run += m; loc[j] = run;
        mask16 |= ((unsigned)m << j); emask16 |= ((unsigned)me << j);
    }
    sums[t] = run; __syncthreads();
    for (int off = 1; off < 256; off <<= 1) {
        int v = (t >= off) ? sums[t - off] : 0;
        __syncthreads();
        sums[t] += v;
        __syncthreads();
    }
    int excl = sums[t] - run;
    #pragma unroll
    for (int j = 0; j < 16; ++j) {
        int i = base + j; int s = i >> 1, k = i & 1;
        if ((mask16 >> j) & 1u) {
            int pos = excl + loc[j];
            if (pos <= CAP) {
                slot_token[((size_t)(e * G + g)) * CAP + (pos - 1)] = s;
                token_c[((size_t)(g * S + s)) * 2 + k] = pos - 1;
            } else {
                token_c[((size_t)(g * S + s)) * 2 + k] = -1;   // over capacity
            }
        } else if ((emask16 >> j) & 1u) {
            token_c[((size_t)(g * S + s)) * 2 + k] = -1;       // padded token
        }
    }
    __syncthreads();
    int total = sums[255];
    for (int i = total + t; i < CAP; i += 256)
        slot_token[((size_t)(e * G + g)) * CAP + i] = -1;      // unfilled slots
}

// ---------------- gather tokens -> X bf16 [E][GC][MDIM] ----------------
__global__ __launch_bounds__(128) void gather_kernel(const float* __restrict__ inp,
                                                     const int* __restrict__ slot_token,
                                                     u16* __restrict__ X) {
    int row = blockIdx.x;
    int t = threadIdx.x;
    int s = slot_token[row];
    int g = (row % GC) / CAP;
    bf16x8 v;
    if (s >= 0) {
        const float* src = inp + ((size_t)(g * S + s)) * MDIM + t * 8;
        f32x4 a = *(const f32x4*)src;
        f32x4 b = *(const f32x4*)(src + 4);
        #pragma unroll
        for (int j = 0; j < 4; ++j) { v[j] = (short)f2bf(a[j]); v[4+j] = (short)f2bf(b[j]); }
    } else {
        #pragma unroll
        for (int j = 0; j < 8; ++j) v[j] = 0;
    }
    *(bf16x8*)(X + (size_t)row * MDIM + t * 8) = v;
}

// ======================================================================
// GEMM1+2 fused (R9-proven, unchanged): 32x32x16, BM=256 BN=128 BK=64,
// ring-2 LDS 128KiB, stage(t+1) || compute(t), vmcnt(0)+barrier per tile.
// ======================================================================
__global__ __launch_bounds__(512, 1) void gemm_ffn12_v9(
        const u16* __restrict__ Xb, const u16* __restrict__ WgT,
        const u16* __restrict__ W0T, u16* __restrict__ Hb) {
    extern __shared__ char smem[];
    const int NK = MDIM / 64;                      // 16
    int bid = blockIdx.x;
    int swz = (bid & 7) * 320 + (bid >> 3);        // bijective (2560 % 8 == 0)
    int mt = swz % 10, nt = (swz / 10) & 31, e = swz / 320;
    const char* A  = (const char*)(Xb  + (size_t)e * GC * MDIM   + (size_t)mt * 256 * MDIM);
    const char* Bg = (const char*)(WgT + (size_t)e * HDIM * MDIM + (size_t)nt * 128 * MDIM);
    const char* B0 = (const char*)(W0T + (size_t)e * HDIM * MDIM + (size_t)nt * 128 * MDIM);
    int tid = threadIdx.x, w = tid >> 6, l = tid & 63;
    int wm = w >> 2, wn = w & 3;
    int lr = l & 31, lk = l >> 5;
    int lswz = ((lr >> 1) & 7) << 4;

    int koff[4];
    #pragma unroll
    for (int ks = 0; ks < 4; ++ks) koff[ks] = (ks * 32 + lk * 16) ^ lswz;
    int baseA[4];
    #pragma unroll
    for (int rb = 0; rb < 4; ++rb) baseA[rb] = (wm * 128 + rb * 32 + lr) * 128;
    int baseB = (wn * 32 + lr) * 128;

    const char* srcA[4]; const char* srcG[2]; const char* srcO[2];
    #pragma unroll
    for (int p = 0; p < 4; ++p) {
        int gr = p * 64 + w * 8 + (l >> 3);
        srcA[p] = A + (size_t)gr * (MDIM * 2) + (((l & 7) * 16) ^ swz128(gr));
    }
    #pragma unroll
    for (int p = 0; p < 2; ++p) {
        int gr = p * 64 + w * 8 + (l >> 3);
        srcG[p] = Bg + (size_t)gr * (MDIM * 2) + (((l & 7) * 16) ^ swz128(gr));
        srcO[p] = B0 + (size_t)gr * (MDIM * 2) + (((l & 7) * 16) ^ swz128(gr));
    }

    f32x16 zz;
    #pragma unroll
    for (int i = 0; i < 16; ++i) zz[i] = 0.f;
    f32x16 ag[4], ao[4];
    #pragma unroll
    for (int rb = 0; rb < 4; ++rb) { ag[rb] = zz; ao[rb] = zz; }

    auto stage = [&](int tt) {
        int kk = tt * 128;
        char* dst = smem + (tt & 1) * 65536;
        #pragma unroll
        for (int p = 0; p < 4; ++p)
            gload16(srcA[p] + kk, dst + (p * 64 + w * 8) * 128);
        #pragma unroll
        for (int p = 0; p < 2; ++p) {
            gload16(srcG[p] + kk, dst + 32768 + (p * 64 + w * 8) * 128);
            gload16(srcO[p] + kk, dst + 49152 + (p * 64 + w * 8) * 128);
        }
    };

    stage(0);
    asm volatile("s_waitcnt vmcnt(0)" ::: "memory");
    BAR();

    #pragma unroll 1
    for (int t = 0; t < NK; ++t) {
        if (t + 1 < NK) stage(t + 1);
        const char* bufc = smem + (t & 1) * 65536;
        #pragma unroll
        for (int ks = 0; ks < 4; ++ks) {
            bf16x8 bg = *(const bf16x8*)(bufc + 32768 + baseB + koff[ks]);
            bf16x8 bo = *(const bf16x8*)(bufc + 49152 + baseB + koff[ks]);
            bf16x8 af[4];
            #pragma unroll
            for (int rb = 0; rb < 4; ++rb)
                af[rb] = *(const bf16x8*)(bufc + baseA[rb] + koff[ks]);
            __builtin_amdgcn_s_setprio(1);
            #pragma unroll
            for (int rb = 0; rb < 4; ++rb) {
                ag[rb] = MFMA32(bg, af[rb], ag[rb]);
                ao[rb] = MFMA32(bo, af[rb], ao[rb]);
            }
            __builtin_amdgcn_s_setprio(0);
        }
        asm volatile("s_waitcnt vmcnt(0)" ::: "memory");
        BAR();
    }

    u16* He = Hb + (size_t)e * GC * HDIM;
    int row0 = mt * 256 + wm * 128 + lr;
    int col0 = nt * 128 + wn * 32 + lk * 4;
    #pragma unroll
    for (int rb = 0; rb < 4; ++rb) {
        size_t rowoff = (size_t)(row0 + rb * 32) * HDIM;
        #pragma unroll
        for (int q = 0; q < 4; ++q) {
            s16x4 pk;
            #pragma unroll
            for (int r = 0; r < 4; ++r) {
                float gv = ag[rb][q * 4 + r], ov = ao[rb][q * 4 + r];
                float hv = gv / (1.f + __expf(-gv)) * ov;
                pk[r] = (short)f2bf(hv);
            }
            *(s16x4*)(He + rowoff + col0 + q * 8) = pk;
        }
    }
}

// ======================================================================
// GEMM3 v10 (retry; R10 crash was prep OOB, proven by R11): 32x32x16,
// BM=320 BN=256 BK=64 -> grid 8x4x8 = 256 blocks = exactly 1/CU, no tail.
// Waves 2Mx4N; wave 160x64 (5rb x 2cb), read:MFMA ratio 1.02.
// ring-2 LDS 144KiB: A 40K @0, B 32K @40960 per buf.
// ======================================================================
__global__ __launch_bounds__(512, 1) void gemm_out_v10(
        const u16* __restrict__ Hb, const u16* __restrict__ WoT,
        float* __restrict__ EO) {
    extern __shared__ char smem[];
    const int NK = HDIM / 64;                      // 64
    int bid = blockIdx.x;
    int swz = (bid & 7) * 32 + (bid >> 3);         // bijective (256 % 8 == 0)
    int e = swz >> 5; int rem = swz & 31; int mt = rem & 7; int nt = rem >> 3;
    const char* A = (const char*)(Hb  + (size_t)e * GC * HDIM   + (size_t)mt * 320 * HDIM);
    const char* B = (const char*)(WoT + (size_t)e * MDIM * HDIM + (size_t)nt * 256 * HDIM);
    int tid = threadIdx.x, w = tid >> 6, l = tid & 63;
    int wm = w >> 2, wn = w & 3;
    int lr = l & 31, lk = l >> 5;
    int lswz = ((lr >> 1) & 7) << 4;

    int koff[4];
    #pragma unroll
    for (int ks = 0; ks < 4; ++ks) koff[ks] = (ks * 32 + lk * 16) ^ lswz;
    int baseA[5], baseB[2];
    #pragma unroll
    for (int rb = 0; rb < 5; ++rb) baseA[rb] = (wm * 160 + rb * 32 + lr) * 128;
    #pragma unroll
    for (int cb = 0; cb < 2; ++cb) baseB[cb] = (wn * 64 + cb * 32 + lr) * 128;

    const char* srcA[5]; const char* srcB[4];
    #pragma unroll
    for (int p = 0; p < 5; ++p) {
        int gr = p * 64 + w * 8 + (l >> 3);
        srcA[p] = A + (size_t)gr * (HDIM * 2) + (((l & 7) * 16) ^ swz128(gr));
    }
    #pragma unroll
    for (int p = 0; p < 4; ++p) {
        int gr = p * 64 + w * 8 + (l >> 3);
        srcB[p] = B + (size_t)gr * (HDIM * 2) + (((l & 7) * 16) ^ swz128(gr));
    }

    f32x16 zz;
    #pragma unroll
    for (int i = 0; i < 16; ++i) zz[i] = 0.f;
    f32x16 acc[5][2];
    #pragma unroll
    for (int i = 0; i < 5; ++i)
        #pragma unroll
        for (int j = 0; j < 2; ++j) acc[i][j] = zz;

    auto stage = [&](int tt) {                     // 9 gloads per thread
        int kk = tt * 128;
        char* dst = smem + (tt & 1) * 73728;
        #pragma unroll
        for (int p = 0; p < 5; ++p)
            gload16(srcA[p] + kk, dst + (p * 64 + w * 8) * 128);
        #pragma unroll
        for (int p = 0; p < 4; ++p)
            gload16(srcB[p] + kk, dst + 40960 + (p * 64 + w * 8) * 128);
    };

    stage(0);
    asm volatile("s_waitcnt vmcnt(0)" ::: "memory");
    BAR();

    #pragma unroll 1
    for (int t = 0; t < NK; ++t) {
        if (t + 1 < NK) stage(t + 1);
        const char* bufc = smem + (t & 1) * 73728;
        #pragma unroll
        for (int ks = 0; ks < 4; ++ks) {
            bf16x8 bf[2], af[5];
            #pragma unroll
            for (int cb = 0; cb < 2; ++cb)
                bf[cb] = *(const bf16x8*)(bufc + 40960 + baseB[cb] + koff[ks]);
            #pragma unroll
            for (int rb = 0; rb < 5; ++rb)
                af[rb] = *(const bf16x8*)(bufc + baseA[rb] + koff[ks]);
            __builtin_amdgcn_s_setprio(1);
            #pragma unroll
            for (int rb = 0; rb < 5; ++rb)
                #pragma unroll
                for (int cb = 0; cb < 2; ++cb)
                    acc[rb][cb] = MFMA32(bf[cb], af[rb], acc[rb][cb]);
            __builtin_amdgcn_s_setprio(0);
        }
        asm volatile("s_waitcnt vmcnt(0)" ::: "memory");
        BAR();
    }

    float* Ee = EO + (size_t)e * GC * MDIM;
    int row0 = mt * 320 + wm * 160 + lr;
    int col0 = nt * 256 + wn * 64 + lk * 4;
    #pragma unroll
    for (int rb = 0; rb < 5; ++rb) {
        size_t rowoff = (size_t)(row0 + rb * 32) * MDIM;
        #pragma unroll
        for (int cb = 0; cb < 2; ++cb)
            #pragma unroll
            for (int q = 0; q < 4; ++q) {
                f32x4 v;
                #pragma unroll
                for (int r = 0; r < 4; ++r) v[r] = acc[rb][cb][q * 4 + r];
                *(f32x4*)(Ee + rowoff + col0 + cb * 32 + q * 8) = v;
            }
    }
}

// ============ combine (blocks 0..8191) + aux_final (block 8192) ============
__global__ __launch_bounds__(256) void combine_aux_kernel(
        const float* __restrict__ EO, const int* __restrict__ top_i,
        const float* __restrict__ top_p, const int* __restrict__ token_c,
        const float* __restrict__ sums, float* __restrict__ out) {
    int bid = blockIdx.x;
    if (bid == G * S) {
        if (threadIdx.x == 0) {
            float lb = 0.f, z = 0.f;
            for (int g = 0; g < G; ++g) {
                for (int e = 0; e < E; ++e)
                    lb += (sums[g*17 + 8 + e] / (float)S) * (sums[g*17 + e] / (float)S);
                z += sums[g*17 + 16];
            }
            lb = lb / (float)(G * E) * (float)(E * E);
            z /= (float)(G * S);
            out[(size_t)G * S * MDIM] = 0.01f * lb + 0.001f * z;
        }
        return;
    }
    int tok = bid, t = threadIdx.x;
    int g = tok >> 11;
    f32x4 acc = {0.f, 0.f, 0.f, 0.f};
    #pragma unroll
    for (int k = 0; k < 2; ++k) {
        int c = token_c[tok * 2 + k];
        if (c >= 0) {
            int e = top_i[tok * 2 + k];
            float p = top_p[tok * 2 + k];
            const float* src = EO + ((size_t)e * GC + g * CAP + c) * MDIM + t * 4;
            f32x4 v = *(const f32x4*)src;
            #pragma unroll
            for (int j = 0; j < 4; ++j) acc[j] += p * v[j];
        }
    }
    *(f32x4*)(out + (size_t)tok * MDIM + t * 4) = acc;
}

extern "C" void kernel_launch(void* const* d_in, const int* in_sizes, int n_in,
                              void* d_out, int out_size, void* d_ws, size_t ws_size,
                              hipStream_t stream) {
    (void)in_sizes; (void)n_in; (void)out_size; (void)ws_size;
    const float* inputs   = (const float*)d_in[0];
    const float* paddings = (const float*)d_in[1];
    const float* router_w = (const float*)d_in[2];
    const float* wi_gate  = (const float*)d_in[3];
    const float* wi_0     = (const float*)d_in[4];
    const float* wo       = (const float*)d_in[5];
    float* out = (float*)d_out;

    char* p = (char*)d_ws;
    u16* WgT = (u16*)p; p += (size_t)E * HDIM * MDIM * 2;
    u16* W0T = (u16*)p; p += (size_t)E * HDIM * MDIM * 2;
    u16* WoT = (u16*)p; p += (size_t)E * HDIM * MDIM * 2;
    u16* Xb  = (u16*)p; p += (size_t)E * GC * MDIM * 2;
    u16* Hb  = (u16*)p; p += (size_t)E * GC * HDIM * 2;
    float* EO = (float*)p; p += (size_t)E * GC * MDIM * 4;
    int*   top_i = (int*)p;   p += (size_t)G * S * TOPK * 4;
    float* top_p = (float*)p; p += (size_t)G * S * TOPK * 4;
    int*   token_c = (int*)p; p += (size_t)G * S * TOPK * 4;
    int*   slot_token = (int*)p; p += (size_t)E * G * CAP * 4;
    float* partials = (float*)p; p += (size_t)RBLK * 17 * 4;
    float* sums = (float*)p; p += 4 * 17 * 4;

    hipFuncSetAttribute((const void*)gemm_ffn12_v9,
                        hipFuncAttributeMaxDynamicSharedMemorySize, 131072);
    hipFuncSetAttribute((const void*)gemm_out_v10,
                        hipFuncAttributeMaxDynamicSharedMemorySize, 147456);

    // router (2048) + wi_gate T (8192) + wi_0 T (8192) + wo T (8192)
    prep_kernel<<<RBLK + 24576, 256, 0, stream>>>(inputs, router_w, wi_gate, wi_0, wo,
                                                  WgT, W0T, WoT, top_i, top_p, partials);
    // scan (32, writes all -1 sentinels) + reduce_partials (4)
    scan_reduce_kernel<<<36, 256, 0, stream>>>(top_i, paddings, partials,
                                               slot_token, token_c, sums);
    gather_kernel<<<E * GC, 128, 0, stream>>>(inputs, slot_token, Xb);
    gemm_ffn12_v9<<<2560, 512, 131072, stream>>>(Xb, WgT, W0T, Hb);
    gemm_out_v10<<<256, 512, 147456, stream>>>(Hb, WoT, EO);
    // combine (8192) + aux_final (1)
    combine_aux_kernel<<<G * S + 1, 256, 0, stream>>>(EO, top_i, top_p, token_c,
                                                      sums, out);
}